// Round 6
// baseline (1840.813 us; speedup 1.0000x reference)
//
#include <hip/hip_runtime.h>

#define N_NODES 200000
#define E_EVENTS 1000000
#define D_DIM 128
#define B_BATCH 50000
#define K_NEI 20

#define NCHUNK 196          // ceil(200000/1024) scan chunks
#define ATTN_UNITS 12500    // 4 b per unit
#define SEG_UNITS 50000     // 4 nodes per unit
#define ATTN_P4 2000        // attn units run during scatter phase

// ---------------- ws layout (int offsets) ----------------------------------
#define WS_COUNTS   0         // [200000]
#define WS_OFFSETS  200000    // [200000]
#define WS_CURSOR   400000    // [200000]
#define WS_CHUNK    600000    // [256]
#define WS_PARTIALS 600320    // float2[196*20] -> 7840 floats
#define WS_BARS     608256    // 8 barriers x 16-int stride
#define WS_PERM     608512    // int2[1M] (TSP=1) or int[1M] (TSP=0)

// ---------------------------------------------------------------------------
// software grid barrier: one fresh counter per use (zeroed by host memset).
// release fence + agent RMW on arrive; agent acquire spin on depart.
// ---------------------------------------------------------------------------
__device__ __forceinline__ void gbar(int* bars, int idx, int G)
{
    __syncthreads();
    if (threadIdx.x == 0) {
        __threadfence();   // agent release: flush XCD L2 to coherent point
        __hip_atomic_fetch_add(&bars[idx * 16], 1, __ATOMIC_RELEASE,
                               __HIP_MEMORY_SCOPE_AGENT);
        while (__hip_atomic_load(&bars[idx * 16], __ATOMIC_ACQUIRE,
                                 __HIP_MEMORY_SCOPE_AGENT) < G)
            __builtin_amdgcn_s_sleep(4);
    }
    __syncthreads();
}

// ---------------------------------------------------------------------------
// attention logits for unit u (4 b's, one per wave) — same math as R5.
// ---------------------------------------------------------------------------
__device__ __forceinline__ void attn_unit(int u, int wid, int lane,
    const float* __restrict__ nei1, const float* __restrict__ nei2,
    float* __restrict__ logits)
{
    int b = u * 4 + wid;
    int c = lane & 31, h = lane >> 5;
    const float4* n2 = reinterpret_cast<const float4*>(nei2) + (size_t)b * (K_NEI * 32);
    float4 acc = make_float4(0.f, 0.f, 0.f, 0.f);
#pragma unroll
    for (int i = 0; i < K_NEI / 2; ++i) {
        float4 v = n2[(2 * i + h) * 32 + c];
        acc.x += v.x; acc.y += v.y; acc.z += v.z; acc.w += v.w;
    }
    float4 s4;
    s4.x = acc.x + __shfl_xor(acc.x, 32);
    s4.y = acc.y + __shfl_xor(acc.y, 32);
    s4.z = acc.z + __shfl_xor(acc.z, 32);
    s4.w = acc.w + __shfl_xor(acc.w, 32);

    const float4* n1 = reinterpret_cast<const float4*>(nei1) + (size_t)b * (K_NEI * 32);
    float p[K_NEI / 2];
#pragma unroll
    for (int i = 0; i < K_NEI / 2; ++i) {
        float4 v = n1[(2 * i + h) * 32 + c];
        float pp = v.x * s4.x + v.y * s4.y + v.z * s4.z + v.w * s4.w;
#pragma unroll
        for (int off = 16; off; off >>= 1) pp += __shfl_xor(pp, off);
        p[i] = pp;
    }
    int sel = c >> 1;
    float v = p[0];
#pragma unroll
    for (int i = 1; i < K_NEI / 2; ++i) v = (sel == i) ? p[i] : v;
    float vf = __shfl(v, ((lane & 1) << 5) + c);
    if (lane < K_NEI) logits[(size_t)b * K_NEI + lane] = vf;
}

// ---------------------------------------------------------------------------
// segment gather-reduce for one node (one wave) — same math as R5.
// ---------------------------------------------------------------------------
template<int TSP>
__device__ __forceinline__ void seg_node(int n, int lane,
    const void* __restrict__ permv, const int* __restrict__ offsets,
    const float* __restrict__ message, const float* __restrict__ ts,
    float* __restrict__ msg_out, float* __restrict__ t_out)
{
    int c = lane & 31, h = lane >> 5;
    int start = offsets[n];
    int end   = (n < N_NODES - 1) ? offsets[n + 1] : E_EVENTS;
    int len   = end - start;

    const float4* msg4 = reinterpret_cast<const float4*>(message);
    float4 acc0 = make_float4(0.f, 0.f, 0.f, 0.f);
    float4 acc1 = make_float4(0.f, 0.f, 0.f, 0.f);
    float tmax = 0.f;

    for (int base = start; base < end; base += 64) {
        int cl = min(end - base, 64);
        int e_l = 0; float t_l = 0.f;
        if (lane < cl) {
            if (TSP) {
                int2 pe = ((const int2*)permv)[base + lane];
                e_l = pe.x; t_l = __int_as_float(pe.y);
            } else {
                e_l = ((const int*)permv)[base + lane];
                t_l = ts[e_l];
            }
        }
        tmax = fmaxf(tmax, t_l);
        int i = 0;
        for (; i + 8 <= cl; i += 8) {
            int eA = __shfl(e_l, i + 0 + h);
            int eB = __shfl(e_l, i + 2 + h);
            int eC = __shfl(e_l, i + 4 + h);
            int eD = __shfl(e_l, i + 6 + h);
            float4 vA = msg4[(size_t)eA * 32 + c];
            float4 vB = msg4[(size_t)eB * 32 + c];
            float4 vC = msg4[(size_t)eC * 32 + c];
            float4 vD = msg4[(size_t)eD * 32 + c];
            acc0.x += vA.x; acc0.y += vA.y; acc0.z += vA.z; acc0.w += vA.w;
            acc1.x += vB.x; acc1.y += vB.y; acc1.z += vB.z; acc1.w += vB.w;
            acc0.x += vC.x; acc0.y += vC.y; acc0.z += vC.z; acc0.w += vC.w;
            acc1.x += vD.x; acc1.y += vD.y; acc1.z += vD.z; acc1.w += vD.w;
        }
        for (; i + 2 <= cl; i += 2) {
            int e = __shfl(e_l, i + h);
            float4 v = msg4[(size_t)e * 32 + c];
            acc0.x += v.x; acc0.y += v.y; acc0.z += v.z; acc0.w += v.w;
        }
        if (i < cl) {
            int e = __shfl(e_l, i);
            if (h == 0) {
                float4 v = msg4[(size_t)e * 32 + c];
                acc0.x += v.x; acc0.y += v.y; acc0.z += v.z; acc0.w += v.w;
            }
        }
    }
    float4 acc = make_float4(acc0.x + acc1.x, acc0.y + acc1.y,
                             acc0.z + acc1.z, acc0.w + acc1.w);
    acc.x += __shfl_xor(acc.x, 32);
    acc.y += __shfl_xor(acc.y, 32);
    acc.z += __shfl_xor(acc.z, 32);
    acc.w += __shfl_xor(acc.w, 32);
    float inv = 1.0f / (float)max(len, 1);
    if (h == 0) {
        reinterpret_cast<float4*>(msg_out)[(size_t)n * 32 + c] =
            make_float4(acc.x * inv, acc.y * inv, acc.z * inv, acc.w * inv);
    }
#pragma unroll
    for (int off = 32; off; off >>= 1) tmax = fmaxf(tmax, __shfl_xor(tmax, off));
    if (lane == 0) t_out[n] = tmax;
}

// ---------------------------------------------------------------------------
// persistent mega-kernel: hist -> scan -> scatter||attn -> seg||attn ->
// softmax partials -> stats+normalize. 7 software grid barriers.
// ---------------------------------------------------------------------------
template<int TSP>
__global__ void __launch_bounds__(256, 8)
mega(const int* __restrict__ ids, const float* __restrict__ message,
     const float* __restrict__ ts,
     const float* __restrict__ nei1, const float* __restrict__ nei2,
     float* __restrict__ msg_out, float* __restrict__ t_out,
     float* __restrict__ score, int* __restrict__ wsi, int G)
{
    int bid = blockIdx.x, t = threadIdx.x;
    int wid = t >> 6, lane = t & 63;

    int*    counts    = wsi + WS_COUNTS;
    int*    offsets   = wsi + WS_OFFSETS;
    int*    cursor    = wsi + WS_CURSOR;
    int*    chunkSums = wsi + WS_CHUNK;
    float2* partials  = (float2*)(wsi + WS_PARTIALS);
    int*    bars      = wsi + WS_BARS;
    void*   permv     = (void*)(wsi + WS_PERM);

    __shared__ float smemf[512];
    __shared__ int   smemi[256];
    __shared__ float stm[K_NEI], sinv[K_NEI];

    // ---- P0: histogram -----------------------------------------------------
    for (int e = bid * 256 + t; e < E_EVENTS; e += G * 256)
        atomicAdd(counts + ids[e], 1);
    gbar(bars, 0, G);

    // ---- P1: chunk sums (1024 counts per chunk) ----------------------------
    for (int cu = bid; cu < NCHUNK; cu += G) {
        int base = cu * 1024 + t * 4, s = 0;
#pragma unroll
        for (int j = 0; j < 4; ++j) { int i = base + j; if (i < N_NODES) s += counts[i]; }
        smemi[t] = s; __syncthreads();
        for (int off = 128; off; off >>= 1) {
            if (t < off) smemi[t] += smemi[t + off];
            __syncthreads();
        }
        if (t == 0) chunkSums[cu] = smemi[0];
        __syncthreads();
    }
    gbar(bars, 1, G);

    // ---- P2: exclusive scan of 196 chunk sums (block 0) --------------------
    if (bid == 0) {
        int v = (t < NCHUNK) ? chunkSums[t] : 0;
        smemi[t] = v; __syncthreads();
        for (int off = 1; off < 256; off <<= 1) {
            int x = (t >= off) ? smemi[t - off] : 0;
            __syncthreads();
            smemi[t] += x;
            __syncthreads();
        }
        if (t < NCHUNK) chunkSums[t] = smemi[t] - v;
    }
    gbar(bars, 2, G);

    // ---- P3: final scan -> offsets, cursor ---------------------------------
    for (int cu = bid; cu < NCHUNK; cu += G) {
        int base = cu * 1024 + t * 4;
        int c0 = (base + 0 < N_NODES) ? counts[base + 0] : 0;
        int c1 = (base + 1 < N_NODES) ? counts[base + 1] : 0;
        int c2 = (base + 2 < N_NODES) ? counts[base + 2] : 0;
        int c3 = (base + 3 < N_NODES) ? counts[base + 3] : 0;
        int tsum = c0 + c1 + c2 + c3;
        smemi[t] = tsum; __syncthreads();
        for (int off = 1; off < 256; off <<= 1) {
            int x = (t >= off) ? smemi[t - off] : 0;
            __syncthreads();
            smemi[t] += x;
            __syncthreads();
        }
        int excl = smemi[t] - tsum + chunkSums[cu];
        if (base + 0 < N_NODES) { offsets[base + 0] = excl; cursor[base + 0] = excl; } excl += c0;
        if (base + 1 < N_NODES) { offsets[base + 1] = excl; cursor[base + 1] = excl; } excl += c1;
        if (base + 2 < N_NODES) { offsets[base + 2] = excl; cursor[base + 2] = excl; } excl += c2;
        if (base + 3 < N_NODES) { offsets[base + 3] = excl; cursor[base + 3] = excl; } excl += c3;
        __syncthreads();
    }
    gbar(bars, 3, G);

    // ---- P4: scatter (lower half) || attn units [0, 2000) (upper half) -----
    {
        int Gs = G >> 1;
        if (bid < Gs) {
            for (int e = bid * 256 + t; e < E_EVENTS; e += Gs * 256) {
                int pos = atomicAdd(cursor + ids[e], 1);
                if (TSP) ((int2*)permv)[pos] = make_int2(e, __float_as_int(ts[e]));
                else     ((int*)permv)[pos]  = e;
            }
        } else {
            for (int u = bid - Gs; u < ATTN_P4; u += G - Gs)
                attn_unit(u, wid, lane, nei1, nei2, score);
        }
    }
    gbar(bars, 4, G);

    // ---- P5: seg gather (50000 units) || attn units [2000, 12500), 5:1 -----
    for (int v = bid; v < 63000; v += G) {
        int q = v / 6, r = v % 6;
        if (r < 5) {
            int s = q * 5 + r;
            if (s < SEG_UNITS)
                seg_node<TSP>(s * 4 + wid, lane, permv, offsets, message, ts,
                              msg_out, t_out);
        } else {
            int a = ATTN_P4 + q;
            if (a < ATTN_UNITS)
                attn_unit(a, wid, lane, nei1, nei2, score);
        }
    }
    gbar(bars, 5, G);

    // ---- P6: softmax block partials (per-column over 256 rows) -------------
    if (bid < NCHUNK) {
        int b = bid * 256 + t;
        bool val = (b < B_BATCH);
        float v[K_NEI];
        if (val) {
            const float4* row = reinterpret_cast<const float4*>(score + (size_t)b * K_NEI);
#pragma unroll
            for (int q = 0; q < 5; ++q) {
                float4 r4 = row[q];
                v[q * 4 + 0] = r4.x; v[q * 4 + 1] = r4.y;
                v[q * 4 + 2] = r4.z; v[q * 4 + 3] = r4.w;
            }
        } else {
#pragma unroll
            for (int k = 0; k < K_NEI; ++k) v[k] = -INFINITY;
        }
#pragma unroll
        for (int k = 0; k < K_NEI; ++k) {
            float m = v[k];
#pragma unroll
            for (int off = 32; off; off >>= 1) m = fmaxf(m, __shfl_xor(m, off));
            if (lane == 0) smemf[wid * K_NEI + k] = m;
        }
        __syncthreads();
        float bmx[K_NEI];
#pragma unroll
        for (int k = 0; k < K_NEI; ++k)
            bmx[k] = fmaxf(fmaxf(smemf[k], smemf[K_NEI + k]),
                           fmaxf(smemf[2 * K_NEI + k], smemf[3 * K_NEI + k]));
#pragma unroll
        for (int k = 0; k < K_NEI; ++k) {
            float e = val ? expf(v[k] - bmx[k]) : 0.f;
#pragma unroll
            for (int off = 32; off; off >>= 1) e += __shfl_xor(e, off);
            if (lane == 0) smemf[128 + wid * K_NEI + k] = e;
        }
        __syncthreads();
        if (t < K_NEI) {
            float m4 = fmaxf(fmaxf(smemf[t], smemf[K_NEI + t]),
                             fmaxf(smemf[2 * K_NEI + t], smemf[3 * K_NEI + t]));
            float s4 = smemf[128 + t] + smemf[128 + K_NEI + t] +
                       smemf[128 + 2 * K_NEI + t] + smemf[128 + 3 * K_NEI + t];
            partials[bid * K_NEI + t] = make_float2(m4, s4);
        }
    }
    gbar(bars, 6, G);

    // ---- P7: redundant stats per block + normalize -------------------------
    {
        float sm = -INFINITY, ss = 0.f;
        if (t < 240) {
            int k = t % K_NEI;
            int c0 = (t / K_NEI) * 17, c1 = min(c0 + 17, NCHUNK);
            for (int j = c0; j < c1; ++j) {
                float2 p = partials[j * K_NEI + k];
                float nm = fmaxf(sm, p.x);
                ss = ss * expf(sm - nm) + p.y * expf(p.x - nm);
                sm = nm;
            }
        }
        __syncthreads();
        if (t < 240) { smemf[t] = sm; smemf[256 + t] = ss; }
        __syncthreads();
        if (t < K_NEI) {
            float m = -INFINITY, s = 0.f;
#pragma unroll
            for (int c2 = 0; c2 < 12; ++c2) {
                float pm = smemf[c2 * K_NEI + t], ps = smemf[256 + c2 * K_NEI + t];
                float nm = fmaxf(m, pm);
                s = s * expf(m - nm) + ps * expf(pm - nm);
                m = nm;
            }
            stm[t] = m; sinv[t] = 1.0f / s;
        }
        __syncthreads();
        for (int i = bid * 256 + t; i < B_BATCH * K_NEI; i += G * 256) {
            int k = i % K_NEI;
            score[i] = expf(score[i] - stm[k]) * sinv[k];
        }
    }
}

extern "C" void kernel_launch(void* const* d_in, const int* in_sizes, int n_in,
                              void* d_out, int out_size, void* d_ws, size_t ws_size,
                              hipStream_t stream)
{
    const int*   node_ids = (const int*)  d_in[0];
    const float* message  = (const float*)d_in[1];
    const float* ts       = (const float*)d_in[2];
    const float* nei1     = (const float*)d_in[3];
    const float* nei2     = (const float*)d_in[4];

    float* out     = (float*)d_out;
    float* msg_out = out;                                   // [N,128]
    float* t_out   = out + (size_t)N_NODES * D_DIM;         // [N]
    float* score   = t_out + N_NODES;                       // [B,K]

    int* wsi = (int*)d_ws;

    // int2 perm needs (608512 + 2M) ints
    bool tsp = ws_size >= ((size_t)WS_PERM + 2u * E_EVENTS) * sizeof(int);

    // zero histogram counts + barrier counters every call (graph-replay safe)
    hipMemsetAsync(wsi + WS_COUNTS, 0, (size_t)N_NODES * sizeof(int), stream);
    hipMemsetAsync(wsi + WS_BARS,   0, 128 * sizeof(int), stream);

    // co-resident grid size: occupancy query x CU count (host-side, capture-safe)
    int numCU = 256;
    hipDeviceGetAttribute(&numCU, hipDeviceAttributeMultiprocessorCount, 0);
    int bpc = 0;
    hipError_t oe;
    if (tsp) oe = hipOccupancyMaxActiveBlocksPerMultiprocessor(
                    &bpc, reinterpret_cast<const void*>(&mega<1>), 256, 0);
    else     oe = hipOccupancyMaxActiveBlocksPerMultiprocessor(
                    &bpc, reinterpret_cast<const void*>(&mega<0>), 256, 0);
    if (oe != hipSuccess || bpc < 1) bpc = 2;   // conservative safe fallback
    int G = bpc * numCU;
    if (G > 2048) G = 2048;

    if (tsp)
        mega<1><<<G, 256, 0, stream>>>(node_ids, message, ts, nei1, nei2,
                                       msg_out, t_out, score, wsi, G);
    else
        mega<0><<<G, 256, 0, stream>>>(node_ids, message, ts, nei1, nei2,
                                       msg_out, t_out, score, wsi, G);
}

// Round 7
// 624.805 us; speedup vs baseline: 2.9462x; 2.9462x over previous
//
#include <hip/hip_runtime.h>

#define N_NODES 200000
#define E_EVENTS 1000000
#define D_DIM 128
#define B_BATCH 50000
#define K_NEI 20
#define NCHUNK 196            // ceil(200000/1024)

// ---------------- ws layout (int offsets) ----------------------------------
#define WS_COUNTS   0         // [200000]
#define WS_OFFSETS  200000    // [200000]
#define WS_CURSOR   400000    // [200000]
#define WS_CHUNK    600000    // [256]
#define WS_PARTIALS 600320    // float2[128*20] -> ends 605440
#define WS_PERM     605440    // int2[1M] (TSP=1) or int[1M] (TSP=0)

// attn slice boundaries (1 unit = 1 block = 4 b's; 12500 units total)
#define A_HIST   1500
#define A_SCANB  2100
#define A_SCANF  2800
#define A_SCAT   6000

#define PB_HIST 512
#define PB_SCAT 512

// ---------------------------------------------------------------------------
// attention logits for unit u (4 b's, one per wave) — R5 code, verified.
// ---------------------------------------------------------------------------
__device__ __forceinline__ void attn_unit(int u, int wid, int lane,
    const float* __restrict__ nei1, const float* __restrict__ nei2,
    float* __restrict__ logits)
{
    int b = u * 4 + wid;
    int c = lane & 31, h = lane >> 5;
    const float4* n2 = reinterpret_cast<const float4*>(nei2) + (size_t)b * (K_NEI * 32);
    float4 acc = make_float4(0.f, 0.f, 0.f, 0.f);
#pragma unroll
    for (int i = 0; i < K_NEI / 2; ++i) {
        float4 v = n2[(2 * i + h) * 32 + c];
        acc.x += v.x; acc.y += v.y; acc.z += v.z; acc.w += v.w;
    }
    float4 s4;
    s4.x = acc.x + __shfl_xor(acc.x, 32);
    s4.y = acc.y + __shfl_xor(acc.y, 32);
    s4.z = acc.z + __shfl_xor(acc.z, 32);
    s4.w = acc.w + __shfl_xor(acc.w, 32);

    const float4* n1 = reinterpret_cast<const float4*>(nei1) + (size_t)b * (K_NEI * 32);
    float p[K_NEI / 2];
#pragma unroll
    for (int i = 0; i < K_NEI / 2; ++i) {
        float4 v = n1[(2 * i + h) * 32 + c];
        float pp = v.x * s4.x + v.y * s4.y + v.z * s4.z + v.w * s4.w;
#pragma unroll
        for (int off = 16; off; off >>= 1) pp += __shfl_xor(pp, off);
        p[i] = pp;
    }
    int sel = c >> 1;
    float v = p[0];
#pragma unroll
    for (int i = 1; i < K_NEI / 2; ++i) v = (sel == i) ? p[i] : v;
    float vf = __shfl(v, ((lane & 1) << 5) + c);
    if (lane < K_NEI) logits[(size_t)b * K_NEI + lane] = vf;
}

// ---------------------------------------------------------------------------
// segment gather-reduce for one node (one wave) — R5 code, verified.
// ---------------------------------------------------------------------------
template<int TSP>
__device__ __forceinline__ void seg_node(int n, int lane,
    const void* __restrict__ permv, const int* __restrict__ offsets,
    const float* __restrict__ message, const float* __restrict__ ts,
    float* __restrict__ msg_out, float* __restrict__ t_out)
{
    int c = lane & 31, h = lane >> 5;
    int start = offsets[n];
    int end   = (n < N_NODES - 1) ? offsets[n + 1] : E_EVENTS;
    int len   = end - start;

    const float4* msg4 = reinterpret_cast<const float4*>(message);
    float4 acc0 = make_float4(0.f, 0.f, 0.f, 0.f);
    float4 acc1 = make_float4(0.f, 0.f, 0.f, 0.f);
    float tmax = 0.f;

    for (int base = start; base < end; base += 64) {
        int cl = min(end - base, 64);
        int e_l = 0; float t_l = 0.f;
        if (lane < cl) {
            if (TSP) {
                int2 pe = ((const int2*)permv)[base + lane];
                e_l = pe.x; t_l = __int_as_float(pe.y);
            } else {
                e_l = ((const int*)permv)[base + lane];
                t_l = ts[e_l];
            }
        }
        tmax = fmaxf(tmax, t_l);
        int i = 0;
        for (; i + 8 <= cl; i += 8) {
            int eA = __shfl(e_l, i + 0 + h);
            int eB = __shfl(e_l, i + 2 + h);
            int eC = __shfl(e_l, i + 4 + h);
            int eD = __shfl(e_l, i + 6 + h);
            float4 vA = msg4[(size_t)eA * 32 + c];
            float4 vB = msg4[(size_t)eB * 32 + c];
            float4 vC = msg4[(size_t)eC * 32 + c];
            float4 vD = msg4[(size_t)eD * 32 + c];
            acc0.x += vA.x; acc0.y += vA.y; acc0.z += vA.z; acc0.w += vA.w;
            acc1.x += vB.x; acc1.y += vB.y; acc1.z += vB.z; acc1.w += vB.w;
            acc0.x += vC.x; acc0.y += vC.y; acc0.z += vC.z; acc0.w += vC.w;
            acc1.x += vD.x; acc1.y += vD.y; acc1.z += vD.z; acc1.w += vD.w;
        }
        for (; i + 2 <= cl; i += 2) {
            int e = __shfl(e_l, i + h);
            float4 v = msg4[(size_t)e * 32 + c];
            acc0.x += v.x; acc0.y += v.y; acc0.z += v.z; acc0.w += v.w;
        }
        if (i < cl) {
            int e = __shfl(e_l, i);
            if (h == 0) {
                float4 v = msg4[(size_t)e * 32 + c];
                acc0.x += v.x; acc0.y += v.y; acc0.z += v.z; acc0.w += v.w;
            }
        }
    }
    float4 acc = make_float4(acc0.x + acc1.x, acc0.y + acc1.y,
                             acc0.z + acc1.z, acc0.w + acc1.w);
    acc.x += __shfl_xor(acc.x, 32);
    acc.y += __shfl_xor(acc.y, 32);
    acc.z += __shfl_xor(acc.z, 32);
    acc.w += __shfl_xor(acc.w, 32);
    float inv = 1.0f / (float)max(len, 1);
    if (h == 0) {
        reinterpret_cast<float4*>(msg_out)[(size_t)n * 32 + c] =
            make_float4(acc.x * inv, acc.y * inv, acc.z * inv, acc.w * inv);
    }
#pragma unroll
    for (int off = 32; off; off >>= 1) tmax = fmaxf(tmax, __shfl_xor(tmax, off));
    if (lane == 0) t_out[n] = tmax;
}

// ---------------------------------------------------------------------------
// K1: histogram (blocks [0,512)) || attn units [0, 1500)
// ---------------------------------------------------------------------------
__global__ void __launch_bounds__(256)
k_hist(const int* __restrict__ ids, int* __restrict__ counts,
       const float* __restrict__ nei1, const float* __restrict__ nei2,
       float* __restrict__ score)
{
    int bid = blockIdx.x, t = threadIdx.x;
    if (bid < PB_HIST) {
        for (int e = bid * 256 + t; e < E_EVENTS; e += PB_HIST * 256)
            atomicAdd(counts + ids[e], 1);
    } else {
        attn_unit(bid - PB_HIST, t >> 6, t & 63, nei1, nei2, score);
    }
}

// ---------------------------------------------------------------------------
// K2: chunk sums (blocks [0,196)) || attn units [1500, 2100)
// ---------------------------------------------------------------------------
__global__ void __launch_bounds__(256)
k_scanb(const int* __restrict__ counts, int* __restrict__ chunkSums,
        const float* __restrict__ nei1, const float* __restrict__ nei2,
        float* __restrict__ score)
{
    int bid = blockIdx.x, t = threadIdx.x;
    if (bid < NCHUNK) {
        __shared__ int sd[256];
        int base = bid * 1024 + t * 4, s = 0;
#pragma unroll
        for (int j = 0; j < 4; ++j) { int i = base + j; if (i < N_NODES) s += counts[i]; }
        sd[t] = s; __syncthreads();
        for (int off = 128; off; off >>= 1) {
            if (t < off) sd[t] += sd[t + off];
            __syncthreads();
        }
        if (t == 0) chunkSums[bid] = sd[0];
    } else {
        attn_unit(A_HIST + (bid - NCHUNK), t >> 6, t & 63, nei1, nei2, score);
    }
}

// ---------------------------------------------------------------------------
// K3: final scan w/ redundant chunk-prefix (blocks [0,196)) || attn [2100,2800)
// ---------------------------------------------------------------------------
__global__ void __launch_bounds__(256)
k_scanf(const int* __restrict__ counts, const int* __restrict__ chunkSums,
        int* __restrict__ offsets, int* __restrict__ cursor,
        const float* __restrict__ nei1, const float* __restrict__ nei2,
        float* __restrict__ score)
{
    int bid = blockIdx.x, t = threadIdx.x;
    if (bid < NCHUNK) {
        __shared__ int sd[256];
        // redundant exclusive prefix over 196 chunk sums (L2-hot, 784 B)
        int v = (t < NCHUNK) ? chunkSums[t] : 0;
        sd[t] = v; __syncthreads();
        for (int off = 1; off < 256; off <<= 1) {
            int x = (t >= off) ? sd[t - off] : 0;
            __syncthreads();
            sd[t] += x;
            __syncthreads();
        }
        int chunkBase = (bid == 0) ? 0 : sd[bid - 1];
        __syncthreads();
        // per-chunk scan of 1024 counts
        int base = bid * 1024 + t * 4;
        int c0 = (base + 0 < N_NODES) ? counts[base + 0] : 0;
        int c1 = (base + 1 < N_NODES) ? counts[base + 1] : 0;
        int c2 = (base + 2 < N_NODES) ? counts[base + 2] : 0;
        int c3 = (base + 3 < N_NODES) ? counts[base + 3] : 0;
        int tsum = c0 + c1 + c2 + c3;
        sd[t] = tsum; __syncthreads();
        for (int off = 1; off < 256; off <<= 1) {
            int x = (t >= off) ? sd[t - off] : 0;
            __syncthreads();
            sd[t] += x;
            __syncthreads();
        }
        int excl = sd[t] - tsum + chunkBase;
        if (base + 0 < N_NODES) { offsets[base + 0] = excl; cursor[base + 0] = excl; } excl += c0;
        if (base + 1 < N_NODES) { offsets[base + 1] = excl; cursor[base + 1] = excl; } excl += c1;
        if (base + 2 < N_NODES) { offsets[base + 2] = excl; cursor[base + 2] = excl; } excl += c2;
        if (base + 3 < N_NODES) { offsets[base + 3] = excl; cursor[base + 3] = excl; } excl += c3;
    } else {
        attn_unit(A_SCANB + (bid - NCHUNK), t >> 6, t & 63, nei1, nei2, score);
    }
}

// ---------------------------------------------------------------------------
// K4: scatter (blocks [0,512)) || attn units [2800, 6000)
// ---------------------------------------------------------------------------
template<int TSP>
__global__ void __launch_bounds__(256)
k_scat(const int* __restrict__ ids, const float* __restrict__ ts,
       int* __restrict__ cursor, void* __restrict__ permv,
       const float* __restrict__ nei1, const float* __restrict__ nei2,
       float* __restrict__ score)
{
    int bid = blockIdx.x, t = threadIdx.x;
    if (bid < PB_SCAT) {
        for (int e = bid * 256 + t; e < E_EVENTS; e += PB_SCAT * 256) {
            int pos = atomicAdd(cursor + ids[e], 1);
            if (TSP) ((int2*)permv)[pos] = make_int2(e, __float_as_int(ts[e]));
            else     ((int*)permv)[pos]  = e;
        }
    } else {
        attn_unit(A_SCANF + (bid - PB_SCAT), t >> 6, t & 63, nei1, nei2, score);
    }
}

// ---------------------------------------------------------------------------
// K5: seg gather-reduce (50000 blocks) || attn units [6000, 12500), 7:1.
// ---------------------------------------------------------------------------
template<int TSP>
__global__ void __launch_bounds__(256, 8)
k_seg(const void* __restrict__ permv, const int* __restrict__ offsets,
      const float* __restrict__ message, const float* __restrict__ ts,
      const float* __restrict__ nei1, const float* __restrict__ nei2,
      float* __restrict__ msg_out, float* __restrict__ t_out,
      float* __restrict__ score)
{
    int v = blockIdx.x, t = threadIdx.x;
    int q = v >> 3, r = v & 7;
    int wid = t >> 6, lane = t & 63;
    if (r < 7) {
        int s = q * 7 + r;
        if (s < 50000)
            seg_node<TSP>(s * 4 + wid, lane, permv, offsets, message, ts,
                          msg_out, t_out);
    } else {
        int u = A_SCAT + q;
        if (u < 12500)
            attn_unit(u, wid, lane, nei1, nei2, score);
    }
}

// ---------------------------------------------------------------------------
// K6: per-block online softmax partials over dim 0 (b). 128 blocks. (R5)
// ---------------------------------------------------------------------------
__global__ void softmax_partial(const float* __restrict__ logits, float2* __restrict__ partials)
{
    int t = threadIdx.x;
    float m[K_NEI], s[K_NEI];
#pragma unroll
    for (int k = 0; k < K_NEI; ++k) { m[k] = -INFINITY; s[k] = 0.f; }

    for (int b = blockIdx.x * 256 + t; b < B_BATCH; b += 128 * 256) {
        const float4* row = reinterpret_cast<const float4*>(logits + (size_t)b * K_NEI);
        float v[K_NEI];
#pragma unroll
        for (int q = 0; q < 5; ++q) {
            float4 rr = row[q];
            v[q * 4 + 0] = rr.x; v[q * 4 + 1] = rr.y; v[q * 4 + 2] = rr.z; v[q * 4 + 3] = rr.w;
        }
#pragma unroll
        for (int k = 0; k < K_NEI; ++k) {
            float nm = fmaxf(m[k], v[k]);
            s[k] = s[k] * expf(m[k] - nm) + expf(v[k] - nm);
            m[k] = nm;
        }
    }
#pragma unroll
    for (int k = 0; k < K_NEI; ++k) {
#pragma unroll
        for (int off = 32; off; off >>= 1) {
            float om = __shfl_xor(m[k], off);
            float os = __shfl_xor(s[k], off);
            float nm = fmaxf(m[k], om);
            s[k] = s[k] * expf(m[k] - nm) + os * expf(om - nm);
            m[k] = nm;
        }
    }
    __shared__ float lm[4][K_NEI], lsum[4][K_NEI];
    int wid = t >> 6, lane = t & 63;
    if (lane == 0) {
#pragma unroll
        for (int k = 0; k < K_NEI; ++k) { lm[wid][k] = m[k]; lsum[wid][k] = s[k]; }
    }
    __syncthreads();
    if (t < K_NEI) {
        float mm = lm[0][t], ss = lsum[0][t];
#pragma unroll
        for (int w = 1; w < 4; ++w) {
            float om = lm[w][t], os = lsum[w][t];
            float nm = fmaxf(mm, om);
            ss = ss * expf(mm - nm) + os * expf(om - nm);
            mm = nm;
        }
        partials[blockIdx.x * K_NEI + t] = make_float2(mm, ss);
    }
}

// ---------------------------------------------------------------------------
// K7: redundant per-block stats over 128 partials + normalize.
// ---------------------------------------------------------------------------
__global__ void __launch_bounds__(256)
k_norm(float* __restrict__ score, const float2* __restrict__ partials)
{
    __shared__ float sm[256], ssum[256];
    __shared__ float stm[K_NEI], sinv[K_NEI];
    int t = threadIdx.x;
    float m = -INFINITY, s = 0.f;
    if (t < 240) {
        int k = t % K_NEI, g = t / K_NEI;
        int j0 = g * 11, j1 = min(j0 + 11, 128);
        for (int j = j0; j < j1; ++j) {
            float2 p = partials[j * K_NEI + k];
            float nm = fmaxf(m, p.x);
            s = s * expf(m - nm) + p.y * expf(p.x - nm);
            m = nm;
        }
    }
    sm[t] = m; ssum[t] = s; __syncthreads();
    if (t < K_NEI) {
        float mm = -INFINITY, ss = 0.f;
#pragma unroll
        for (int g = 0; g < 12; ++g) {
            float pm = sm[g * K_NEI + t], ps = ssum[g * K_NEI + t];
            float nm = fmaxf(mm, pm);
            ss = ss * expf(mm - nm) + ps * expf(pm - nm);
            mm = nm;
        }
        stm[t] = mm; sinv[t] = 1.0f / ss;
    }
    __syncthreads();
    int i = blockIdx.x * 256 + t;
    if (i < B_BATCH * K_NEI) {
        int k = i % K_NEI;
        score[i] = expf(score[i] - stm[k]) * sinv[k];
    }
}

extern "C" void kernel_launch(void* const* d_in, const int* in_sizes, int n_in,
                              void* d_out, int out_size, void* d_ws, size_t ws_size,
                              hipStream_t stream)
{
    const int*   node_ids = (const int*)  d_in[0];
    const float* message  = (const float*)d_in[1];
    const float* ts       = (const float*)d_in[2];
    const float* nei1     = (const float*)d_in[3];
    const float* nei2     = (const float*)d_in[4];

    float* out     = (float*)d_out;
    float* msg_out = out;                                   // [N,128]
    float* t_out   = out + (size_t)N_NODES * D_DIM;         // [N]
    float* score   = t_out + N_NODES;                       // [B,K]

    int*    wsi       = (int*)d_ws;
    int*    counts    = wsi + WS_COUNTS;
    int*    offsets   = wsi + WS_OFFSETS;
    int*    cursor    = wsi + WS_CURSOR;
    int*    chunkSums = wsi + WS_CHUNK;
    float2* partials  = (float2*)(wsi + WS_PARTIALS);
    void*   permv     = (void*)(wsi + WS_PERM);

    bool tsp = ws_size >= ((size_t)WS_PERM + 2u * E_EVENTS) * sizeof(int);

    hipMemsetAsync(counts, 0, (size_t)N_NODES * sizeof(int), stream);

    k_hist<<<PB_HIST + A_HIST, 256, 0, stream>>>(node_ids, counts, nei1, nei2, score);
    k_scanb<<<NCHUNK + (A_SCANB - A_HIST), 256, 0, stream>>>(counts, chunkSums, nei1, nei2, score);
    k_scanf<<<NCHUNK + (A_SCANF - A_SCANB), 256, 0, stream>>>(counts, chunkSums, offsets, cursor,
                                                              nei1, nei2, score);
    if (tsp) {
        k_scat<1><<<PB_SCAT + (A_SCAT - A_SCANF), 256, 0, stream>>>(
            node_ids, ts, cursor, permv, nei1, nei2, score);
        k_seg<1><<<57144, 256, 0, stream>>>(
            permv, offsets, message, ts, nei1, nei2, msg_out, t_out, score);
    } else {
        k_scat<0><<<PB_SCAT + (A_SCAT - A_SCANF), 256, 0, stream>>>(
            node_ids, ts, cursor, permv, nei1, nei2, score);
        k_seg<0><<<57144, 256, 0, stream>>>(
            permv, offsets, message, ts, nei1, nei2, msg_out, t_out, score);
    }

    softmax_partial<<<128, 256, 0, stream>>>(score, partials);
    k_norm<<<(B_BATCH * K_NEI + 255) / 256, 256, 0, stream>>>(score, partials);
}

// Round 8
// 493.092 us; speedup vs baseline: 3.7332x; 1.2671x over previous
//
#include <hip/hip_runtime.h>

#define N_NODES 200000
#define E_EVENTS 1000000
#define D_DIM 128
#define B_BATCH 50000
#define K_NEI 20
#define NCHUNK 196            // ceil(200000/1024)

// ---------------- ws layout (int offsets) ----------------------------------
#define WS_COUNTS   0         // [200000]
#define WS_OFFSETS  200000    // [200000]
#define WS_CURSOR   400000    // [200000]
#define WS_CHUNK    600000    // [256]
#define WS_PARTIALS 600320    // float2[128*20] -> ends 605440
#define WS_PERM     605440    // int2[1M] (TSP=1) or int[1M] (TSP=0)

// ---------------------------------------------------------------------------
// attention logits for unit u (4 b's, one per wave) — verified R5.
// ---------------------------------------------------------------------------
__device__ __forceinline__ void attn_unit(int u, int wid, int lane,
    const float* __restrict__ nei1, const float* __restrict__ nei2,
    float* __restrict__ logits)
{
    int b = u * 4 + wid;
    int c = lane & 31, h = lane >> 5;
    const float4* n2 = reinterpret_cast<const float4*>(nei2) + (size_t)b * (K_NEI * 32);
    float4 acc = make_float4(0.f, 0.f, 0.f, 0.f);
#pragma unroll
    for (int i = 0; i < K_NEI / 2; ++i) {
        float4 v = n2[(2 * i + h) * 32 + c];
        acc.x += v.x; acc.y += v.y; acc.z += v.z; acc.w += v.w;
    }
    float4 s4;
    s4.x = acc.x + __shfl_xor(acc.x, 32);
    s4.y = acc.y + __shfl_xor(acc.y, 32);
    s4.z = acc.z + __shfl_xor(acc.z, 32);
    s4.w = acc.w + __shfl_xor(acc.w, 32);

    const float4* n1 = reinterpret_cast<const float4*>(nei1) + (size_t)b * (K_NEI * 32);
    float p[K_NEI / 2];
#pragma unroll
    for (int i = 0; i < K_NEI / 2; ++i) {
        float4 v = n1[(2 * i + h) * 32 + c];
        float pp = v.x * s4.x + v.y * s4.y + v.z * s4.z + v.w * s4.w;
#pragma unroll
        for (int off = 16; off; off >>= 1) pp += __shfl_xor(pp, off);
        p[i] = pp;
    }
    int sel = c >> 1;
    float v = p[0];
#pragma unroll
    for (int i = 1; i < K_NEI / 2; ++i) v = (sel == i) ? p[i] : v;
    float vf = __shfl(v, ((lane & 1) << 5) + c);
    if (lane < K_NEI) logits[(size_t)b * K_NEI + lane] = vf;
}

// ---------------------------------------------------------------------------
// segment gather-reduce for one node (one wave) — verified R5.
// ---------------------------------------------------------------------------
template<int TSP>
__device__ __forceinline__ void seg_node(int n, int lane,
    const void* __restrict__ permv, const int* __restrict__ offsets,
    const float* __restrict__ message, const float* __restrict__ ts,
    float* __restrict__ msg_out, float* __restrict__ t_out)
{
    int c = lane & 31, h = lane >> 5;
    int start = offsets[n];
    int end   = (n < N_NODES - 1) ? offsets[n + 1] : E_EVENTS;
    int len   = end - start;

    const float4* msg4 = reinterpret_cast<const float4*>(message);
    float4 acc0 = make_float4(0.f, 0.f, 0.f, 0.f);
    float4 acc1 = make_float4(0.f, 0.f, 0.f, 0.f);
    float tmax = 0.f;

    for (int base = start; base < end; base += 64) {
        int cl = min(end - base, 64);
        int e_l = 0; float t_l = 0.f;
        if (lane < cl) {
            if (TSP) {
                int2 pe = ((const int2*)permv)[base + lane];
                e_l = pe.x; t_l = __int_as_float(pe.y);
            } else {
                e_l = ((const int*)permv)[base + lane];
                t_l = ts[e_l];
            }
        }
        tmax = fmaxf(tmax, t_l);
        int i = 0;
        for (; i + 8 <= cl; i += 8) {
            int eA = __shfl(e_l, i + 0 + h);
            int eB = __shfl(e_l, i + 2 + h);
            int eC = __shfl(e_l, i + 4 + h);
            int eD = __shfl(e_l, i + 6 + h);
            float4 vA = msg4[(size_t)eA * 32 + c];
            float4 vB = msg4[(size_t)eB * 32 + c];
            float4 vC = msg4[(size_t)eC * 32 + c];
            float4 vD = msg4[(size_t)eD * 32 + c];
            acc0.x += vA.x; acc0.y += vA.y; acc0.z += vA.z; acc0.w += vA.w;
            acc1.x += vB.x; acc1.y += vB.y; acc1.z += vB.z; acc1.w += vB.w;
            acc0.x += vC.x; acc0.y += vC.y; acc0.z += vC.z; acc0.w += vC.w;
            acc1.x += vD.x; acc1.y += vD.y; acc1.z += vD.z; acc1.w += vD.w;
        }
        for (; i + 2 <= cl; i += 2) {
            int e = __shfl(e_l, i + h);
            float4 v = msg4[(size_t)e * 32 + c];
            acc0.x += v.x; acc0.y += v.y; acc0.z += v.z; acc0.w += v.w;
        }
        if (i < cl) {
            int e = __shfl(e_l, i);
            if (h == 0) {
                float4 v = msg4[(size_t)e * 32 + c];
                acc0.x += v.x; acc0.y += v.y; acc0.z += v.z; acc0.w += v.w;
            }
        }
    }
    float4 acc = make_float4(acc0.x + acc1.x, acc0.y + acc1.y,
                             acc0.z + acc1.z, acc0.w + acc1.w);
    acc.x += __shfl_xor(acc.x, 32);
    acc.y += __shfl_xor(acc.y, 32);
    acc.z += __shfl_xor(acc.z, 32);
    acc.w += __shfl_xor(acc.w, 32);
    float inv = 1.0f / (float)max(len, 1);
    if (h == 0) {
        reinterpret_cast<float4*>(msg_out)[(size_t)n * 32 + c] =
            make_float4(acc.x * inv, acc.y * inv, acc.z * inv, acc.w * inv);
    }
#pragma unroll
    for (int off = 32; off; off >>= 1) tmax = fmaxf(tmax, __shfl_xor(tmax, off));
    if (lane == 0) t_out[n] = tmax;
}

// ---------------------------------------------------------------------------
// K1: histogram of node ids (512 blocks, grid-stride)
// ---------------------------------------------------------------------------
__global__ void __launch_bounds__(256)
k_hist(const int* __restrict__ ids, int* __restrict__ counts)
{
    for (int e = blockIdx.x * 256 + threadIdx.x; e < E_EVENTS; e += 512 * 256)
        atomicAdd(counts + ids[e], 1);
}

// ---------------------------------------------------------------------------
// K2: per-chunk sums (196 blocks, 1024 counts each)
// ---------------------------------------------------------------------------
__global__ void __launch_bounds__(256)
k_scanb(const int* __restrict__ counts, int* __restrict__ chunkSums)
{
    __shared__ int sd[256];
    int t = threadIdx.x, base = blockIdx.x * 1024 + t * 4;
    int s = 0;
#pragma unroll
    for (int j = 0; j < 4; ++j) { int i = base + j; if (i < N_NODES) s += counts[i]; }
    sd[t] = s; __syncthreads();
    for (int off = 128; off; off >>= 1) {
        if (t < off) sd[t] += sd[t + off];
        __syncthreads();
    }
    if (t == 0) chunkSums[blockIdx.x] = sd[0];
}

// ---------------------------------------------------------------------------
// K3: final scan w/ redundant chunk-prefix per block — verified R7.
// ---------------------------------------------------------------------------
__global__ void __launch_bounds__(256)
k_scanf(const int* __restrict__ counts, const int* __restrict__ chunkSums,
        int* __restrict__ offsets, int* __restrict__ cursor)
{
    __shared__ int sd[256];
    int bid = blockIdx.x, t = threadIdx.x;
    // redundant exclusive prefix over 196 chunk sums (L2-hot, 784 B)
    int v = (t < NCHUNK) ? chunkSums[t] : 0;
    sd[t] = v; __syncthreads();
    for (int off = 1; off < 256; off <<= 1) {
        int x = (t >= off) ? sd[t - off] : 0;
        __syncthreads();
        sd[t] += x;
        __syncthreads();
    }
    int chunkBase = (bid == 0) ? 0 : sd[bid - 1];
    __syncthreads();
    // per-chunk scan of 1024 counts
    int base = bid * 1024 + t * 4;
    int c0 = (base + 0 < N_NODES) ? counts[base + 0] : 0;
    int c1 = (base + 1 < N_NODES) ? counts[base + 1] : 0;
    int c2 = (base + 2 < N_NODES) ? counts[base + 2] : 0;
    int c3 = (base + 3 < N_NODES) ? counts[base + 3] : 0;
    int tsum = c0 + c1 + c2 + c3;
    sd[t] = tsum; __syncthreads();
    for (int off = 1; off < 256; off <<= 1) {
        int x = (t >= off) ? sd[t - off] : 0;
        __syncthreads();
        sd[t] += x;
        __syncthreads();
    }
    int excl = sd[t] - tsum + chunkBase;
    if (base + 0 < N_NODES) { offsets[base + 0] = excl; cursor[base + 0] = excl; } excl += c0;
    if (base + 1 < N_NODES) { offsets[base + 1] = excl; cursor[base + 1] = excl; } excl += c1;
    if (base + 2 < N_NODES) { offsets[base + 2] = excl; cursor[base + 2] = excl; } excl += c2;
    if (base + 3 < N_NODES) { offsets[base + 3] = excl; cursor[base + 3] = excl; } excl += c3;
}

// ---------------------------------------------------------------------------
// K4: scatter (event, ts) into CSR order (512 blocks, grid-stride)
// ---------------------------------------------------------------------------
template<int TSP>
__global__ void __launch_bounds__(256)
k_scat(const int* __restrict__ ids, const float* __restrict__ ts,
       int* __restrict__ cursor, void* __restrict__ permv)
{
    for (int e = blockIdx.x * 256 + threadIdx.x; e < E_EVENTS; e += 512 * 256) {
        int pos = atomicAdd(cursor + ids[e], 1);
        if (TSP) ((int2*)permv)[pos] = make_int2(e, __float_as_int(ts[e]));
        else     ((int*)permv)[pos]  = e;
    }
}

// ---------------------------------------------------------------------------
// K5: FUSED seg+attn. 12500 groups of 3: r<2 -> seg pair-block (8 nodes,
//     each wave handles nodes n0+wid and n0+wid+4 — two independent gather
//     streams for 2x memory-level parallelism); r=2 -> attn unit g.
// ---------------------------------------------------------------------------
template<int TSP>
__global__ void __launch_bounds__(256, 8)
seg_attn(const void* __restrict__ permv, const int* __restrict__ offsets,
         const float* __restrict__ message, const float* __restrict__ ts,
         const float* __restrict__ nei1, const float* __restrict__ nei2,
         float* __restrict__ msg_out, float* __restrict__ t_out,
         float* __restrict__ logits)
{
    int g = blockIdx.x / 3, r = blockIdx.x % 3;
    int t = threadIdx.x;
    int wid = t >> 6, lane = t & 63;

    if (r < 2) {
        int n0 = (g * 2 + r) * 8;          // 25000 pairs x 8 = 200000 exact
        seg_node<TSP>(n0 + wid,     lane, permv, offsets, message, ts, msg_out, t_out);
        seg_node<TSP>(n0 + 4 + wid, lane, permv, offsets, message, ts, msg_out, t_out);
    } else {
        attn_unit(g, wid, lane, nei1, nei2, logits);   // g in [0,12500)
    }
}

// ---------------------------------------------------------------------------
// K6: per-block online softmax partials over dim 0 (b). 128 blocks. (R5)
// ---------------------------------------------------------------------------
__global__ void softmax_partial(const float* __restrict__ logits, float2* __restrict__ partials)
{
    int t = threadIdx.x;
    float m[K_NEI], s[K_NEI];
#pragma unroll
    for (int k = 0; k < K_NEI; ++k) { m[k] = -INFINITY; s[k] = 0.f; }

    for (int b = blockIdx.x * 256 + t; b < B_BATCH; b += 128 * 256) {
        const float4* row = reinterpret_cast<const float4*>(logits + (size_t)b * K_NEI);
        float v[K_NEI];
#pragma unroll
        for (int q = 0; q < 5; ++q) {
            float4 rr = row[q];
            v[q * 4 + 0] = rr.x; v[q * 4 + 1] = rr.y; v[q * 4 + 2] = rr.z; v[q * 4 + 3] = rr.w;
        }
#pragma unroll
        for (int k = 0; k < K_NEI; ++k) {
            float nm = fmaxf(m[k], v[k]);
            s[k] = s[k] * expf(m[k] - nm) + expf(v[k] - nm);
            m[k] = nm;
        }
    }
#pragma unroll
    for (int k = 0; k < K_NEI; ++k) {
#pragma unroll
        for (int off = 32; off; off >>= 1) {
            float om = __shfl_xor(m[k], off);
            float os = __shfl_xor(s[k], off);
            float nm = fmaxf(m[k], om);
            s[k] = s[k] * expf(m[k] - nm) + os * expf(om - nm);
            m[k] = nm;
        }
    }
    __shared__ float lm[4][K_NEI], lsum[4][K_NEI];
    int wid = t >> 6, lane = t & 63;
    if (lane == 0) {
#pragma unroll
        for (int k = 0; k < K_NEI; ++k) { lm[wid][k] = m[k]; lsum[wid][k] = s[k]; }
    }
    __syncthreads();
    if (t < K_NEI) {
        float mm = lm[0][t], ss = lsum[0][t];
#pragma unroll
        for (int w = 1; w < 4; ++w) {
            float om = lm[w][t], os = lsum[w][t];
            float nm = fmaxf(mm, om);
            ss = ss * expf(mm - nm) + os * expf(om - nm);
            mm = nm;
        }
        partials[blockIdx.x * K_NEI + t] = make_float2(mm, ss);
    }
}

// ---------------------------------------------------------------------------
// K7: redundant per-block stats over 128 partials + normalize — verified R7.
// ---------------------------------------------------------------------------
__global__ void __launch_bounds__(256)
k_norm(float* __restrict__ score, const float2* __restrict__ partials)
{
    __shared__ float sm[256], ssum[256];
    __shared__ float stm[K_NEI], sinv[K_NEI];
    int t = threadIdx.x;
    float m = -INFINITY, s = 0.f;
    if (t < 240) {
        int k = t % K_NEI, g = t / K_NEI;
        int j0 = g * 11, j1 = min(j0 + 11, 128);
        for (int j = j0; j < j1; ++j) {
            float2 p = partials[j * K_NEI + k];
            float nm = fmaxf(m, p.x);
            s = s * expf(m - nm) + p.y * expf(p.x - nm);
            m = nm;
        }
    }
    sm[t] = m; ssum[t] = s; __syncthreads();
    if (t < K_NEI) {
        float mm = -INFINITY, ss = 0.f;
#pragma unroll
        for (int g = 0; g < 12; ++g) {
            float pm = sm[g * K_NEI + t], ps = ssum[g * K_NEI + t];
            float nm = fmaxf(mm, pm);
            ss = ss * expf(mm - nm) + ps * expf(pm - nm);
            mm = nm;
        }
        stm[t] = mm; sinv[t] = 1.0f / ss;
    }
    __syncthreads();
    int i = blockIdx.x * 256 + t;
    if (i < B_BATCH * K_NEI) {
        int k = i % K_NEI;
        score[i] = expf(score[i] - stm[k]) * sinv[k];
    }
}

extern "C" void kernel_launch(void* const* d_in, const int* in_sizes, int n_in,
                              void* d_out, int out_size, void* d_ws, size_t ws_size,
                              hipStream_t stream)
{
    const int*   node_ids = (const int*)  d_in[0];
    const float* message  = (const float*)d_in[1];
    const float* ts       = (const float*)d_in[2];
    const float* nei1     = (const float*)d_in[3];
    const float* nei2     = (const float*)d_in[4];

    float* out     = (float*)d_out;
    float* msg_out = out;                                   // [N,128]
    float* t_out   = out + (size_t)N_NODES * D_DIM;         // [N]
    float* score   = t_out + N_NODES;                       // [B,K]

    int*    wsi       = (int*)d_ws;
    int*    counts    = wsi + WS_COUNTS;
    int*    offsets   = wsi + WS_OFFSETS;
    int*    cursor    = wsi + WS_CURSOR;
    int*    chunkSums = wsi + WS_CHUNK;
    float2* partials  = (float2*)(wsi + WS_PARTIALS);
    void*   permv     = (void*)(wsi + WS_PERM);

    bool tsp = ws_size >= ((size_t)WS_PERM + 2u * E_EVENTS) * sizeof(int);

    hipMemsetAsync(counts, 0, (size_t)N_NODES * sizeof(int), stream);

    k_hist<<<512, 256, 0, stream>>>(node_ids, counts);
    k_scanb<<<NCHUNK, 256, 0, stream>>>(counts, chunkSums);
    k_scanf<<<NCHUNK, 256, 0, stream>>>(counts, chunkSums, offsets, cursor);

    if (tsp) {
        k_scat<1><<<512, 256, 0, stream>>>(node_ids, ts, cursor, permv);
        seg_attn<1><<<37500, 256, 0, stream>>>(
            permv, offsets, message, ts, nei1, nei2, msg_out, t_out, score);
    } else {
        k_scat<0><<<512, 256, 0, stream>>>(node_ids, ts, cursor, permv);
        seg_attn<0><<<37500, 256, 0, stream>>>(
            permv, offsets, message, ts, nei1, nei2, msg_out, t_out, score);
    }

    softmax_partial<<<128, 256, 0, stream>>>(score, partials);
    k_norm<<<(B_BATCH * K_NEI + 255) / 256, 256, 0, stream>>>(score, partials);
}

// Round 9
// 471.783 us; speedup vs baseline: 3.9018x; 1.0452x over previous
//
#include <hip/hip_runtime.h>

#define N_NODES 200000
#define E_EVENTS 1000000
#define D_DIM 128
#define B_BATCH 50000
#define K_NEI 20
#define NCHUNK 196            // ceil(200000/1024)

// ---------------- ws layout (int offsets) ----------------------------------
#define WS_COUNTS   0         // [200000]
#define WS_OFFSETS  200000    // [200000]
#define WS_CURSOR   400000    // [200000]
#define WS_CHUNK    600000    // [256]
#define WS_PARTIALS 600320    // float2[128*20] -> ends 605440
#define WS_PERM     605440    // int2[1M] (TSP=1) or int[1M] (TSP=0)

// ---------------------------------------------------------------------------
// attention logits for unit u (4 b's, one per wave) — verified R5/R8.
// ---------------------------------------------------------------------------
__device__ __forceinline__ void attn_unit(int u, int wid, int lane,
    const float* __restrict__ nei1, const float* __restrict__ nei2,
    float* __restrict__ logits)
{
    int b = u * 4 + wid;
    int c = lane & 31, h = lane >> 5;
    const float4* n2 = reinterpret_cast<const float4*>(nei2) + (size_t)b * (K_NEI * 32);
    float4 acc = make_float4(0.f, 0.f, 0.f, 0.f);
#pragma unroll
    for (int i = 0; i < K_NEI / 2; ++i) {
        float4 v = n2[(2 * i + h) * 32 + c];
        acc.x += v.x; acc.y += v.y; acc.z += v.z; acc.w += v.w;
    }
    float4 s4;
    s4.x = acc.x + __shfl_xor(acc.x, 32);
    s4.y = acc.y + __shfl_xor(acc.y, 32);
    s4.z = acc.z + __shfl_xor(acc.z, 32);
    s4.w = acc.w + __shfl_xor(acc.w, 32);

    const float4* n1 = reinterpret_cast<const float4*>(nei1) + (size_t)b * (K_NEI * 32);
    float p[K_NEI / 2];
#pragma unroll
    for (int i = 0; i < K_NEI / 2; ++i) {
        float4 v = n1[(2 * i + h) * 32 + c];
        float pp = v.x * s4.x + v.y * s4.y + v.z * s4.z + v.w * s4.w;
#pragma unroll
        for (int off = 16; off; off >>= 1) pp += __shfl_xor(pp, off);
        p[i] = pp;
    }
    int sel = c >> 1;
    float v = p[0];
#pragma unroll
    for (int i = 1; i < K_NEI / 2; ++i) v = (sel == i) ? p[i] : v;
    float vf = __shfl(v, ((lane & 1) << 5) + c);
    if (lane < K_NEI) logits[(size_t)b * K_NEI + lane] = vf;
}

// ---------------------------------------------------------------------------
// segment gather-reduce for one node (one wave) — verified R5/R8.
// ---------------------------------------------------------------------------
template<int TSP>
__device__ __forceinline__ void seg_node(int n, int lane,
    const void* __restrict__ permv, const int* __restrict__ offsets,
    const float* __restrict__ message, const float* __restrict__ ts,
    float* __restrict__ msg_out, float* __restrict__ t_out)
{
    int c = lane & 31, h = lane >> 5;
    int start = offsets[n];
    int end   = (n < N_NODES - 1) ? offsets[n + 1] : E_EVENTS;
    int len   = end - start;

    const float4* msg4 = reinterpret_cast<const float4*>(message);
    float4 acc0 = make_float4(0.f, 0.f, 0.f, 0.f);
    float4 acc1 = make_float4(0.f, 0.f, 0.f, 0.f);
    float tmax = 0.f;

    for (int base = start; base < end; base += 64) {
        int cl = min(end - base, 64);
        int e_l = 0; float t_l = 0.f;
        if (lane < cl) {
            if (TSP) {
                int2 pe = ((const int2*)permv)[base + lane];
                e_l = pe.x; t_l = __int_as_float(pe.y);
            } else {
                e_l = ((const int*)permv)[base + lane];
                t_l = ts[e_l];
            }
        }
        tmax = fmaxf(tmax, t_l);
        int i = 0;
        for (; i + 8 <= cl; i += 8) {
            int eA = __shfl(e_l, i + 0 + h);
            int eB = __shfl(e_l, i + 2 + h);
            int eC = __shfl(e_l, i + 4 + h);
            int eD = __shfl(e_l, i + 6 + h);
            float4 vA = msg4[(size_t)eA * 32 + c];
            float4 vB = msg4[(size_t)eB * 32 + c];
            float4 vC = msg4[(size_t)eC * 32 + c];
            float4 vD = msg4[(size_t)eD * 32 + c];
            acc0.x += vA.x; acc0.y += vA.y; acc0.z += vA.z; acc0.w += vA.w;
            acc1.x += vB.x; acc1.y += vB.y; acc1.z += vB.z; acc1.w += vB.w;
            acc0.x += vC.x; acc0.y += vC.y; acc0.z += vC.z; acc0.w += vC.w;
            acc1.x += vD.x; acc1.y += vD.y; acc1.z += vD.z; acc1.w += vD.w;
        }
        for (; i + 2 <= cl; i += 2) {
            int e = __shfl(e_l, i + h);
            float4 v = msg4[(size_t)e * 32 + c];
            acc0.x += v.x; acc0.y += v.y; acc0.z += v.z; acc0.w += v.w;
        }
        if (i < cl) {
            int e = __shfl(e_l, i);
            if (h == 0) {
                float4 v = msg4[(size_t)e * 32 + c];
                acc0.x += v.x; acc0.y += v.y; acc0.z += v.z; acc0.w += v.w;
            }
        }
    }
    float4 acc = make_float4(acc0.x + acc1.x, acc0.y + acc1.y,
                             acc0.z + acc1.z, acc0.w + acc1.w);
    acc.x += __shfl_xor(acc.x, 32);
    acc.y += __shfl_xor(acc.y, 32);
    acc.z += __shfl_xor(acc.z, 32);
    acc.w += __shfl_xor(acc.w, 32);
    float inv = 1.0f / (float)max(len, 1);
    if (h == 0) {
        reinterpret_cast<float4*>(msg_out)[(size_t)n * 32 + c] =
            make_float4(acc.x * inv, acc.y * inv, acc.z * inv, acc.w * inv);
    }
#pragma unroll
    for (int off = 32; off; off >>= 1) tmax = fmaxf(tmax, __shfl_xor(tmax, off));
    if (lane == 0) t_out[n] = tmax;
}

// ---------------------------------------------------------------------------
// K1: histogram of node ids — full width (1 thread/event, R5-proven)
// ---------------------------------------------------------------------------
__global__ void k_hist(const int* __restrict__ ids, int* __restrict__ counts)
{
    int e = blockIdx.x * blockDim.x + threadIdx.x;
    if (e < E_EVENTS) atomicAdd(counts + ids[e], 1);
}

// ---------------------------------------------------------------------------
// K2: per-chunk sums (196 blocks, 1024 counts each)
// ---------------------------------------------------------------------------
__global__ void __launch_bounds__(256)
k_scanb(const int* __restrict__ counts, int* __restrict__ chunkSums)
{
    __shared__ int sd[256];
    int t = threadIdx.x, base = blockIdx.x * 1024 + t * 4;
    int s = 0;
#pragma unroll
    for (int j = 0; j < 4; ++j) { int i = base + j; if (i < N_NODES) s += counts[i]; }
    sd[t] = s; __syncthreads();
    for (int off = 128; off; off >>= 1) {
        if (t < off) sd[t] += sd[t + off];
        __syncthreads();
    }
    if (t == 0) chunkSums[blockIdx.x] = sd[0];
}

// ---------------------------------------------------------------------------
// K3: final scan w/ redundant chunk-prefix per block — verified R7/R8.
// ---------------------------------------------------------------------------
__global__ void __launch_bounds__(256)
k_scanf(const int* __restrict__ counts, const int* __restrict__ chunkSums,
        int* __restrict__ offsets, int* __restrict__ cursor)
{
    __shared__ int sd[256];
    int bid = blockIdx.x, t = threadIdx.x;
    // redundant exclusive prefix over 196 chunk sums (L2-hot, 784 B)
    int v = (t < NCHUNK) ? chunkSums[t] : 0;
    sd[t] = v; __syncthreads();
    for (int off = 1; off < 256; off <<= 1) {
        int x = (t >= off) ? sd[t - off] : 0;
        __syncthreads();
        sd[t] += x;
        __syncthreads();
    }
    int chunkBase = (bid == 0) ? 0 : sd[bid - 1];
    __syncthreads();
    // per-chunk scan of 1024 counts
    int base = bid * 1024 + t * 4;
    int c0 = (base + 0 < N_NODES) ? counts[base + 0] : 0;
    int c1 = (base + 1 < N_NODES) ? counts[base + 1] : 0;
    int c2 = (base + 2 < N_NODES) ? counts[base + 2] : 0;
    int c3 = (base + 3 < N_NODES) ? counts[base + 3] : 0;
    int tsum = c0 + c1 + c2 + c3;
    sd[t] = tsum; __syncthreads();
    for (int off = 1; off < 256; off <<= 1) {
        int x = (t >= off) ? sd[t - off] : 0;
        __syncthreads();
        sd[t] += x;
        __syncthreads();
    }
    int excl = sd[t] - tsum + chunkBase;
    if (base + 0 < N_NODES) { offsets[base + 0] = excl; cursor[base + 0] = excl; } excl += c0;
    if (base + 1 < N_NODES) { offsets[base + 1] = excl; cursor[base + 1] = excl; } excl += c1;
    if (base + 2 < N_NODES) { offsets[base + 2] = excl; cursor[base + 2] = excl; } excl += c2;
    if (base + 3 < N_NODES) { offsets[base + 3] = excl; cursor[base + 3] = excl; } excl += c3;
}

// ---------------------------------------------------------------------------
// K4: scatter (event, ts) into CSR order — full width (R5-proven)
// ---------------------------------------------------------------------------
template<int TSP>
__global__ void k_scat(const int* __restrict__ ids, const float* __restrict__ ts,
                       int* __restrict__ cursor, void* __restrict__ permv)
{
    int e = blockIdx.x * blockDim.x + threadIdx.x;
    if (e < E_EVENTS) {
        int pos = atomicAdd(cursor + ids[e], 1);
        if (TSP) ((int2*)permv)[pos] = make_int2(e, __float_as_int(ts[e]));
        else     ((int*)permv)[pos]  = e;
    }
}

// ---------------------------------------------------------------------------
// K5: FUSED seg+attn — R5's exact 5-block-group structure (366 us proven).
//     12500 groups of 5: r=0..3 -> seg (4 nodes, one per wave); r=4 -> attn.
// ---------------------------------------------------------------------------
template<int TSP>
__global__ void __launch_bounds__(256, 8)
seg_attn(const void* __restrict__ permv, const int* __restrict__ offsets,
         const float* __restrict__ message, const float* __restrict__ ts,
         const float* __restrict__ nei1, const float* __restrict__ nei2,
         float* __restrict__ msg_out, float* __restrict__ t_out,
         float* __restrict__ logits)
{
    int g = blockIdx.x / 5, r = blockIdx.x % 5;
    int t = threadIdx.x;
    int wid = t >> 6, lane = t & 63;

    if (r < 4) {
        int n = (g * 4 + r) * 4 + wid;            // covers 200000 exactly
        seg_node<TSP>(n, lane, permv, offsets, message, ts, msg_out, t_out);
    } else {
        attn_unit(g, wid, lane, nei1, nei2, logits);   // g in [0,12500)
    }
}

// ---------------------------------------------------------------------------
// K6: per-block online softmax partials over dim 0 (b). 128 blocks. (R5)
// ---------------------------------------------------------------------------
__global__ void softmax_partial(const float* __restrict__ logits, float2* __restrict__ partials)
{
    int t = threadIdx.x;
    float m[K_NEI], s[K_NEI];
#pragma unroll
    for (int k = 0; k < K_NEI; ++k) { m[k] = -INFINITY; s[k] = 0.f; }

    for (int b = blockIdx.x * 256 + t; b < B_BATCH; b += 128 * 256) {
        const float4* row = reinterpret_cast<const float4*>(logits + (size_t)b * K_NEI);
        float v[K_NEI];
#pragma unroll
        for (int q = 0; q < 5; ++q) {
            float4 rr = row[q];
            v[q * 4 + 0] = rr.x; v[q * 4 + 1] = rr.y; v[q * 4 + 2] = rr.z; v[q * 4 + 3] = rr.w;
        }
#pragma unroll
        for (int k = 0; k < K_NEI; ++k) {
            float nm = fmaxf(m[k], v[k]);
            s[k] = s[k] * expf(m[k] - nm) + expf(v[k] - nm);
            m[k] = nm;
        }
    }
#pragma unroll
    for (int k = 0; k < K_NEI; ++k) {
#pragma unroll
        for (int off = 32; off; off >>= 1) {
            float om = __shfl_xor(m[k], off);
            float os = __shfl_xor(s[k], off);
            float nm = fmaxf(m[k], om);
            s[k] = s[k] * expf(m[k] - nm) + os * expf(om - nm);
            m[k] = nm;
        }
    }
    __shared__ float lm[4][K_NEI], lsum[4][K_NEI];
    int wid = t >> 6, lane = t & 63;
    if (lane == 0) {
#pragma unroll
        for (int k = 0; k < K_NEI; ++k) { lm[wid][k] = m[k]; lsum[wid][k] = s[k]; }
    }
    __syncthreads();
    if (t < K_NEI) {
        float mm = lm[0][t], ss = lsum[0][t];
#pragma unroll
        for (int w = 1; w < 4; ++w) {
            float om = lm[w][t], os = lsum[w][t];
            float nm = fmaxf(mm, om);
            ss = ss * expf(mm - nm) + os * expf(om - nm);
            mm = nm;
        }
        partials[blockIdx.x * K_NEI + t] = make_float2(mm, ss);
    }
}

// ---------------------------------------------------------------------------
// K7: redundant per-block stats over 128 partials + normalize — verified R7/R8.
// ---------------------------------------------------------------------------
__global__ void __launch_bounds__(256)
k_norm(float* __restrict__ score, const float2* __restrict__ partials)
{
    __shared__ float sm[256], ssum[256];
    __shared__ float stm[K_NEI], sinv[K_NEI];
    int t = threadIdx.x;
    float m = -INFINITY, s = 0.f;
    if (t < 240) {
        int k = t % K_NEI, g = t / K_NEI;
        int j0 = g * 11, j1 = min(j0 + 11, 128);
        for (int j = j0; j < j1; ++j) {
            float2 p = partials[j * K_NEI + k];
            float nm = fmaxf(m, p.x);
            s = s * expf(m - nm) + p.y * expf(p.x - nm);
            m = nm;
        }
    }
    sm[t] = m; ssum[t] = s; __syncthreads();
    if (t < K_NEI) {
        float mm = -INFINITY, ss = 0.f;
#pragma unroll
        for (int g = 0; g < 12; ++g) {
            float pm = sm[g * K_NEI + t], ps = ssum[g * K_NEI + t];
            float nm = fmaxf(mm, pm);
            ss = ss * expf(mm - nm) + ps * expf(pm - nm);
            mm = nm;
        }
        stm[t] = mm; sinv[t] = 1.0f / ss;
    }
    __syncthreads();
    int i = blockIdx.x * 256 + t;
    if (i < B_BATCH * K_NEI) {
        int k = i % K_NEI;
        score[i] = expf(score[i] - stm[k]) * sinv[k];
    }
}

extern "C" void kernel_launch(void* const* d_in, const int* in_sizes, int n_in,
                              void* d_out, int out_size, void* d_ws, size_t ws_size,
                              hipStream_t stream)
{
    const int*   node_ids = (const int*)  d_in[0];
    const float* message  = (const float*)d_in[1];
    const float* ts       = (const float*)d_in[2];
    const float* nei1     = (const float*)d_in[3];
    const float* nei2     = (const float*)d_in[4];

    float* out     = (float*)d_out;
    float* msg_out = out;                                   // [N,128]
    float* t_out   = out + (size_t)N_NODES * D_DIM;         // [N]
    float* score   = t_out + N_NODES;                       // [B,K]

    int*    wsi       = (int*)d_ws;
    int*    counts    = wsi + WS_COUNTS;
    int*    offsets   = wsi + WS_OFFSETS;
    int*    cursor    = wsi + WS_CURSOR;
    int*    chunkSums = wsi + WS_CHUNK;
    float2* partials  = (float2*)(wsi + WS_PARTIALS);
    void*   permv     = (void*)(wsi + WS_PERM);

    bool tsp = ws_size >= ((size_t)WS_PERM + 2u * E_EVENTS) * sizeof(int);

    hipMemsetAsync(counts, 0, (size_t)N_NODES * sizeof(int), stream);

    k_hist<<<(E_EVENTS + 255) / 256, 256, 0, stream>>>(node_ids, counts);
    k_scanb<<<NCHUNK, 256, 0, stream>>>(counts, chunkSums);
    k_scanf<<<NCHUNK, 256, 0, stream>>>(counts, chunkSums, offsets, cursor);

    if (tsp) {
        k_scat<1><<<(E_EVENTS + 255) / 256, 256, 0, stream>>>(node_ids, ts, cursor, permv);
        seg_attn<1><<<12500 * 5, 256, 0, stream>>>(
            permv, offsets, message, ts, nei1, nei2, msg_out, t_out, score);
    } else {
        k_scat<0><<<(E_EVENTS + 255) / 256, 256, 0, stream>>>(node_ids, ts, cursor, permv);
        seg_attn<0><<<12500 * 5, 256, 0, stream>>>(
            permv, offsets, message, ts, nei1, nei2, msg_out, t_out, score);
    }

    softmax_partial<<<128, 256, 0, stream>>>(score, partials);
    k_norm<<<(B_BATCH * K_NEI + 255) / 256, 256, 0, stream>>>(score, partials);
}

// Round 10
// 439.132 us; speedup vs baseline: 4.1919x; 1.0744x over previous
//
#include <hip/hip_runtime.h>

#define N_NODES 200000
#define E_EVENTS 1000000
#define D_DIM 128
#define B_BATCH 50000
#define K_NEI 20
#define NCHUNK 196            // ceil(200000/1024)
#define SLOTS_PER_NODE 32

// ---------------- ws layout A: slot path (needs ~52 MB) --------------------
#define WA_CURSOR   0         // int[200000]
#define WA_PARTIALS 200064    // float2[128*20] -> 5120 floats, ends 205184
#define WA_SLOTS    205440    // int2[200000*32] = 12.8M ints (8B aligned)

// ---------------- ws layout B: CSR fallback (R9-proven) --------------------
#define WB_COUNTS   0         // [200000]
#define WB_OFFSETS  200000    // [200000]
#define WB_CURSOR   400000    // [200000]
#define WB_CHUNK    600000    // [256]
#define WB_PARTIALS 600320    // float2[128*20] -> ends 605440
#define WB_PERM     605440    // int2[1M] (TSP=1) or int[1M] (TSP=0)

// ---------------------------------------------------------------------------
// attention logits for unit u (4 b's, one per wave) — verified R5/R8/R9.
// ---------------------------------------------------------------------------
__device__ __forceinline__ void attn_unit(int u, int wid, int lane,
    const float* __restrict__ nei1, const float* __restrict__ nei2,
    float* __restrict__ logits)
{
    int b = u * 4 + wid;
    int c = lane & 31, h = lane >> 5;
    const float4* n2 = reinterpret_cast<const float4*>(nei2) + (size_t)b * (K_NEI * 32);
    float4 acc = make_float4(0.f, 0.f, 0.f, 0.f);
#pragma unroll
    for (int i = 0; i < K_NEI / 2; ++i) {
        float4 v = n2[(2 * i + h) * 32 + c];
        acc.x += v.x; acc.y += v.y; acc.z += v.z; acc.w += v.w;
    }
    float4 s4;
    s4.x = acc.x + __shfl_xor(acc.x, 32);
    s4.y = acc.y + __shfl_xor(acc.y, 32);
    s4.z = acc.z + __shfl_xor(acc.z, 32);
    s4.w = acc.w + __shfl_xor(acc.w, 32);

    const float4* n1 = reinterpret_cast<const float4*>(nei1) + (size_t)b * (K_NEI * 32);
    float p[K_NEI / 2];
#pragma unroll
    for (int i = 0; i < K_NEI / 2; ++i) {
        float4 v = n1[(2 * i + h) * 32 + c];
        float pp = v.x * s4.x + v.y * s4.y + v.z * s4.z + v.w * s4.w;
#pragma unroll
        for (int off = 16; off; off >>= 1) pp += __shfl_xor(pp, off);
        p[i] = pp;
    }
    int sel = c >> 1;
    float v = p[0];
#pragma unroll
    for (int i = 1; i < K_NEI / 2; ++i) v = (sel == i) ? p[i] : v;
    float vf = __shfl(v, ((lane & 1) << 5) + c);
    if (lane < K_NEI) logits[(size_t)b * K_NEI + lane] = vf;
}

// ---------------------------------------------------------------------------
// SLOT-path segment reduce: one wave per node. cnt and slot loads issue in
// parallel (slot addresses don't depend on cnt) — one fewer serial round-trip
// than the CSR path.
// ---------------------------------------------------------------------------
__device__ __forceinline__ void seg_node_slots(int n, int lane,
    const int2* __restrict__ slots, const int* __restrict__ cursor,
    const float* __restrict__ message,
    float* __restrict__ msg_out, float* __restrict__ t_out)
{
    int c = lane & 31, h = lane >> 5;
    int cnt = cursor[n];                                  // wave-uniform
    int2 pe = slots[(size_t)n * SLOTS_PER_NODE + c];      // independent of cnt
    int cl = min(cnt, SLOTS_PER_NODE);

    int   e_l = pe.x;
    float t_l = (c < cl) ? __int_as_float(pe.y) : 0.f;

    const float4* msg4 = reinterpret_cast<const float4*>(message);
    float4 acc0 = make_float4(0.f, 0.f, 0.f, 0.f);
    float4 acc1 = make_float4(0.f, 0.f, 0.f, 0.f);
    float tmax = t_l;                                     // dup halves: max-safe

    int i = 0;
    for (; i + 8 <= cl; i += 8) {
        int eA = __shfl(e_l, i + 0 + h);
        int eB = __shfl(e_l, i + 2 + h);
        int eC = __shfl(e_l, i + 4 + h);
        int eD = __shfl(e_l, i + 6 + h);
        float4 vA = msg4[(size_t)eA * 32 + c];
        float4 vB = msg4[(size_t)eB * 32 + c];
        float4 vC = msg4[(size_t)eC * 32 + c];
        float4 vD = msg4[(size_t)eD * 32 + c];
        acc0.x += vA.x; acc0.y += vA.y; acc0.z += vA.z; acc0.w += vA.w;
        acc1.x += vB.x; acc1.y += vB.y; acc1.z += vB.z; acc1.w += vB.w;
        acc0.x += vC.x; acc0.y += vC.y; acc0.z += vC.z; acc0.w += vC.w;
        acc1.x += vD.x; acc1.y += vD.y; acc1.z += vD.z; acc1.w += vD.w;
    }
    for (; i + 2 <= cl; i += 2) {
        int e = __shfl(e_l, i + h);
        float4 v = msg4[(size_t)e * 32 + c];
        acc0.x += v.x; acc0.y += v.y; acc0.z += v.z; acc0.w += v.w;
    }
    if (i < cl) {
        int e = __shfl(e_l, i);
        if (h == 0) {
            float4 v = msg4[(size_t)e * 32 + c];
            acc0.x += v.x; acc0.y += v.y; acc0.z += v.z; acc0.w += v.w;
        }
    }

    float4 acc = make_float4(acc0.x + acc1.x, acc0.y + acc1.y,
                             acc0.z + acc1.z, acc0.w + acc1.w);
    acc.x += __shfl_xor(acc.x, 32);
    acc.y += __shfl_xor(acc.y, 32);
    acc.z += __shfl_xor(acc.z, 32);
    acc.w += __shfl_xor(acc.w, 32);
    float inv = 1.0f / (float)max(cnt, 1);
    if (h == 0) {
        reinterpret_cast<float4*>(msg_out)[(size_t)n * 32 + c] =
            make_float4(acc.x * inv, acc.y * inv, acc.z * inv, acc.w * inv);
    }
#pragma unroll
    for (int off = 32; off; off >>= 1) tmax = fmaxf(tmax, __shfl_xor(tmax, off));
    if (lane == 0) t_out[n] = tmax;
}

// ---------------------------------------------------------------------------
// SLOT-path scatter: the entire CSR build in one kernel (replaces hist +
// scanb + scanf + scat). 1 thread/event.
// ---------------------------------------------------------------------------
__global__ void k_scat_slots(const int* __restrict__ ids, const float* __restrict__ ts,
                             int* __restrict__ cursor, int2* __restrict__ slots)
{
    int e = blockIdx.x * blockDim.x + threadIdx.x;
    if (e < E_EVENTS) {
        int id = ids[e];
        int pos = atomicAdd(cursor + id, 1);
        if (pos < SLOTS_PER_NODE)
            slots[(size_t)id * SLOTS_PER_NODE + pos] = make_int2(e, __float_as_int(ts[e]));
    }
}

// ---------------------------------------------------------------------------
// SLOT-path fused seg+attn — R5's proven 5-block-group structure.
// ---------------------------------------------------------------------------
__global__ void __launch_bounds__(256, 8)
seg_attn_slots(const int2* __restrict__ slots, const int* __restrict__ cursor,
               const float* __restrict__ message,
               const float* __restrict__ nei1, const float* __restrict__ nei2,
               float* __restrict__ msg_out, float* __restrict__ t_out,
               float* __restrict__ logits)
{
    int g = blockIdx.x / 5, r = blockIdx.x % 5;
    int t = threadIdx.x;
    int wid = t >> 6, lane = t & 63;

    if (r < 4) {
        int n = (g * 4 + r) * 4 + wid;            // covers 200000 exactly
        seg_node_slots(n, lane, slots, cursor, message, msg_out, t_out);
    } else {
        attn_unit(g, wid, lane, nei1, nei2, logits);   // g in [0,12500)
    }
}

// ============================ CSR FALLBACK (R9) =============================
template<int TSP>
__device__ __forceinline__ void seg_node(int n, int lane,
    const void* __restrict__ permv, const int* __restrict__ offsets,
    const float* __restrict__ message, const float* __restrict__ ts,
    float* __restrict__ msg_out, float* __restrict__ t_out)
{
    int c = lane & 31, h = lane >> 5;
    int start = offsets[n];
    int end   = (n < N_NODES - 1) ? offsets[n + 1] : E_EVENTS;
    int len   = end - start;

    const float4* msg4 = reinterpret_cast<const float4*>(message);
    float4 acc0 = make_float4(0.f, 0.f, 0.f, 0.f);
    float4 acc1 = make_float4(0.f, 0.f, 0.f, 0.f);
    float tmax = 0.f;

    for (int base = start; base < end; base += 64) {
        int cl = min(end - base, 64);
        int e_l = 0; float t_l = 0.f;
        if (lane < cl) {
            if (TSP) {
                int2 pe = ((const int2*)permv)[base + lane];
                e_l = pe.x; t_l = __int_as_float(pe.y);
            } else {
                e_l = ((const int*)permv)[base + lane];
                t_l = ts[e_l];
            }
        }
        tmax = fmaxf(tmax, t_l);
        int i = 0;
        for (; i + 8 <= cl; i += 8) {
            int eA = __shfl(e_l, i + 0 + h);
            int eB = __shfl(e_l, i + 2 + h);
            int eC = __shfl(e_l, i + 4 + h);
            int eD = __shfl(e_l, i + 6 + h);
            float4 vA = msg4[(size_t)eA * 32 + c];
            float4 vB = msg4[(size_t)eB * 32 + c];
            float4 vC = msg4[(size_t)eC * 32 + c];
            float4 vD = msg4[(size_t)eD * 32 + c];
            acc0.x += vA.x; acc0.y += vA.y; acc0.z += vA.z; acc0.w += vA.w;
            acc1.x += vB.x; acc1.y += vB.y; acc1.z += vB.z; acc1.w += vB.w;
            acc0.x += vC.x; acc0.y += vC.y; acc0.z += vC.z; acc0.w += vC.w;
            acc1.x += vD.x; acc1.y += vD.y; acc1.z += vD.z; acc1.w += vD.w;
        }
        for (; i + 2 <= cl; i += 2) {
            int e = __shfl(e_l, i + h);
            float4 v = msg4[(size_t)e * 32 + c];
            acc0.x += v.x; acc0.y += v.y; acc0.z += v.z; acc0.w += v.w;
        }
        if (i < cl) {
            int e = __shfl(e_l, i);
            if (h == 0) {
                float4 v = msg4[(size_t)e * 32 + c];
                acc0.x += v.x; acc0.y += v.y; acc0.z += v.z; acc0.w += v.w;
            }
        }
    }
    float4 acc = make_float4(acc0.x + acc1.x, acc0.y + acc1.y,
                             acc0.z + acc1.z, acc0.w + acc1.w);
    acc.x += __shfl_xor(acc.x, 32);
    acc.y += __shfl_xor(acc.y, 32);
    acc.z += __shfl_xor(acc.z, 32);
    acc.w += __shfl_xor(acc.w, 32);
    float inv = 1.0f / (float)max(len, 1);
    if (h == 0) {
        reinterpret_cast<float4*>(msg_out)[(size_t)n * 32 + c] =
            make_float4(acc.x * inv, acc.y * inv, acc.z * inv, acc.w * inv);
    }
#pragma unroll
    for (int off = 32; off; off >>= 1) tmax = fmaxf(tmax, __shfl_xor(tmax, off));
    if (lane == 0) t_out[n] = tmax;
}

__global__ void k_hist(const int* __restrict__ ids, int* __restrict__ counts)
{
    int e = blockIdx.x * blockDim.x + threadIdx.x;
    if (e < E_EVENTS) atomicAdd(counts + ids[e], 1);
}

__global__ void __launch_bounds__(256)
k_scanb(const int* __restrict__ counts, int* __restrict__ chunkSums)
{
    __shared__ int sd[256];
    int t = threadIdx.x, base = blockIdx.x * 1024 + t * 4;
    int s = 0;
#pragma unroll
    for (int j = 0; j < 4; ++j) { int i = base + j; if (i < N_NODES) s += counts[i]; }
    sd[t] = s; __syncthreads();
    for (int off = 128; off; off >>= 1) {
        if (t < off) sd[t] += sd[t + off];
        __syncthreads();
    }
    if (t == 0) chunkSums[blockIdx.x] = sd[0];
}

__global__ void __launch_bounds__(256)
k_scanf(const int* __restrict__ counts, const int* __restrict__ chunkSums,
        int* __restrict__ offsets, int* __restrict__ cursor)
{
    __shared__ int sd[256];
    int bid = blockIdx.x, t = threadIdx.x;
    int v = (t < NCHUNK) ? chunkSums[t] : 0;
    sd[t] = v; __syncthreads();
    for (int off = 1; off < 256; off <<= 1) {
        int x = (t >= off) ? sd[t - off] : 0;
        __syncthreads();
        sd[t] += x;
        __syncthreads();
    }
    int chunkBase = (bid == 0) ? 0 : sd[bid - 1];
    __syncthreads();
    int base = bid * 1024 + t * 4;
    int c0 = (base + 0 < N_NODES) ? counts[base + 0] : 0;
    int c1 = (base + 1 < N_NODES) ? counts[base + 1] : 0;
    int c2 = (base + 2 < N_NODES) ? counts[base + 2] : 0;
    int c3 = (base + 3 < N_NODES) ? counts[base + 3] : 0;
    int tsum = c0 + c1 + c2 + c3;
    sd[t] = tsum; __syncthreads();
    for (int off = 1; off < 256; off <<= 1) {
        int x = (t >= off) ? sd[t - off] : 0;
        __syncthreads();
        sd[t] += x;
        __syncthreads();
    }
    int excl = sd[t] - tsum + chunkBase;
    if (base + 0 < N_NODES) { offsets[base + 0] = excl; cursor[base + 0] = excl; } excl += c0;
    if (base + 1 < N_NODES) { offsets[base + 1] = excl; cursor[base + 1] = excl; } excl += c1;
    if (base + 2 < N_NODES) { offsets[base + 2] = excl; cursor[base + 2] = excl; } excl += c2;
    if (base + 3 < N_NODES) { offsets[base + 3] = excl; cursor[base + 3] = excl; } excl += c3;
}

template<int TSP>
__global__ void k_scat(const int* __restrict__ ids, const float* __restrict__ ts,
                       int* __restrict__ cursor, void* __restrict__ permv)
{
    int e = blockIdx.x * blockDim.x + threadIdx.x;
    if (e < E_EVENTS) {
        int pos = atomicAdd(cursor + ids[e], 1);
        if (TSP) ((int2*)permv)[pos] = make_int2(e, __float_as_int(ts[e]));
        else     ((int*)permv)[pos]  = e;
    }
}

template<int TSP>
__global__ void __launch_bounds__(256, 8)
seg_attn(const void* __restrict__ permv, const int* __restrict__ offsets,
         const float* __restrict__ message, const float* __restrict__ ts,
         const float* __restrict__ nei1, const float* __restrict__ nei2,
         float* __restrict__ msg_out, float* __restrict__ t_out,
         float* __restrict__ logits)
{
    int g = blockIdx.x / 5, r = blockIdx.x % 5;
    int t = threadIdx.x;
    int wid = t >> 6, lane = t & 63;

    if (r < 4) {
        int n = (g * 4 + r) * 4 + wid;
        seg_node<TSP>(n, lane, permv, offsets, message, ts, msg_out, t_out);
    } else {
        attn_unit(g, wid, lane, nei1, nei2, logits);
    }
}
// ========================== end CSR fallback ================================

// ---------------------------------------------------------------------------
// softmax tail (shared): per-block partials + redundant-stats normalize.
// ---------------------------------------------------------------------------
__global__ void softmax_partial(const float* __restrict__ logits, float2* __restrict__ partials)
{
    int t = threadIdx.x;
    float m[K_NEI], s[K_NEI];
#pragma unroll
    for (int k = 0; k < K_NEI; ++k) { m[k] = -INFINITY; s[k] = 0.f; }

    for (int b = blockIdx.x * 256 + t; b < B_BATCH; b += 128 * 256) {
        const float4* row = reinterpret_cast<const float4*>(logits + (size_t)b * K_NEI);
        float v[K_NEI];
#pragma unroll
        for (int q = 0; q < 5; ++q) {
            float4 rr = row[q];
            v[q * 4 + 0] = rr.x; v[q * 4 + 1] = rr.y; v[q * 4 + 2] = rr.z; v[q * 4 + 3] = rr.w;
        }
#pragma unroll
        for (int k = 0; k < K_NEI; ++k) {
            float nm = fmaxf(m[k], v[k]);
            s[k] = s[k] * expf(m[k] - nm) + expf(v[k] - nm);
            m[k] = nm;
        }
    }
#pragma unroll
    for (int k = 0; k < K_NEI; ++k) {
#pragma unroll
        for (int off = 32; off; off >>= 1) {
            float om = __shfl_xor(m[k], off);
            float os = __shfl_xor(s[k], off);
            float nm = fmaxf(m[k], om);
            s[k] = s[k] * expf(m[k] - nm) + os * expf(om - nm);
            m[k] = nm;
        }
    }
    __shared__ float lm[4][K_NEI], lsum[4][K_NEI];
    int wid = t >> 6, lane = t & 63;
    if (lane == 0) {
#pragma unroll
        for (int k = 0; k < K_NEI; ++k) { lm[wid][k] = m[k]; lsum[wid][k] = s[k]; }
    }
    __syncthreads();
    if (t < K_NEI) {
        float mm = lm[0][t], ss = lsum[0][t];
#pragma unroll
        for (int w = 1; w < 4; ++w) {
            float om = lm[w][t], os = lsum[w][t];
            float nm = fmaxf(mm, om);
            ss = ss * expf(mm - nm) + os * expf(om - nm);
            mm = nm;
        }
        partials[blockIdx.x * K_NEI + t] = make_float2(mm, ss);
    }
}

__global__ void __launch_bounds__(256)
k_norm(float* __restrict__ score, const float2* __restrict__ partials)
{
    __shared__ float sm[256], ssum[256];
    __shared__ float stm[K_NEI], sinv[K_NEI];
    int t = threadIdx.x;
    float m = -INFINITY, s = 0.f;
    if (t < 240) {
        int k = t % K_NEI, g = t / K_NEI;
        int j0 = g * 11, j1 = min(j0 + 11, 128);
        for (int j = j0; j < j1; ++j) {
            float2 p = partials[j * K_NEI + k];
            float nm = fmaxf(m, p.x);
            s = s * expf(m - nm) + p.y * expf(p.x - nm);
            m = nm;
        }
    }
    sm[t] = m; ssum[t] = s; __syncthreads();
    if (t < K_NEI) {
        float mm = -INFINITY, ss = 0.f;
#pragma unroll
        for (int g = 0; g < 12; ++g) {
            float pm = sm[g * K_NEI + t], ps = ssum[g * K_NEI + t];
            float nm = fmaxf(mm, pm);
            ss = ss * expf(mm - nm) + ps * expf(pm - nm);
            mm = nm;
        }
        stm[t] = mm; sinv[t] = 1.0f / ss;
    }
    __syncthreads();
    int i = blockIdx.x * 256 + t;
    if (i < B_BATCH * K_NEI) {
        int k = i % K_NEI;
        score[i] = expf(score[i] - stm[k]) * sinv[k];
    }
}

extern "C" void kernel_launch(void* const* d_in, const int* in_sizes, int n_in,
                              void* d_out, int out_size, void* d_ws, size_t ws_size,
                              hipStream_t stream)
{
    const int*   node_ids = (const int*)  d_in[0];
    const float* message  = (const float*)d_in[1];
    const float* ts       = (const float*)d_in[2];
    const float* nei1     = (const float*)d_in[3];
    const float* nei2     = (const float*)d_in[4];

    float* out     = (float*)d_out;
    float* msg_out = out;                                   // [N,128]
    float* t_out   = out + (size_t)N_NODES * D_DIM;         // [N]
    float* score   = t_out + N_NODES;                       // [B,K]

    int* wsi = (int*)d_ws;

    // slot path needs cursor + partials + 200000*32 int2 slots
    size_t slots_need = ((size_t)WA_SLOTS + 2u * (size_t)N_NODES * SLOTS_PER_NODE) * sizeof(int);

    if (ws_size >= slots_need) {
        int*    cursor   = wsi + WA_CURSOR;
        float2* partials = (float2*)(wsi + WA_PARTIALS);
        int2*   slots    = (int2*)(wsi + WA_SLOTS);

        hipMemsetAsync(cursor, 0, (size_t)N_NODES * sizeof(int), stream);

        k_scat_slots<<<(E_EVENTS + 255) / 256, 256, 0, stream>>>(node_ids, ts, cursor, slots);
        seg_attn_slots<<<12500 * 5, 256, 0, stream>>>(
            slots, cursor, message, nei1, nei2, msg_out, t_out, score);
        softmax_partial<<<128, 256, 0, stream>>>(score, partials);
        k_norm<<<(B_BATCH * K_NEI + 255) / 256, 256, 0, stream>>>(score, partials);
    } else {
        // -------- CSR fallback (R9-proven) ----------------------------------
        int*    counts    = wsi + WB_COUNTS;
        int*    offsets   = wsi + WB_OFFSETS;
        int*    cursor    = wsi + WB_CURSOR;
        int*    chunkSums = wsi + WB_CHUNK;
        float2* partials  = (float2*)(wsi + WB_PARTIALS);
        void*   permv     = (void*)(wsi + WB_PERM);

        bool tsp = ws_size >= ((size_t)WB_PERM + 2u * E_EVENTS) * sizeof(int);

        hipMemsetAsync(counts, 0, (size_t)N_NODES * sizeof(int), stream);

        k_hist<<<(E_EVENTS + 255) / 256, 256, 0, stream>>>(node_ids, counts);
        k_scanb<<<NCHUNK, 256, 0, stream>>>(counts, chunkSums);
        k_scanf<<<NCHUNK, 256, 0, stream>>>(counts, chunkSums, offsets, cursor);

        if (tsp) {
            k_scat<1><<<(E_EVENTS + 255) / 256, 256, 0, stream>>>(node_ids, ts, cursor, permv);
            seg_attn<1><<<12500 * 5, 256, 0, stream>>>(
                permv, offsets, message, ts, nei1, nei2, msg_out, t_out, score);
        } else {
            k_scat<0><<<(E_EVENTS + 255) / 256, 256, 0, stream>>>(node_ids, ts, cursor, permv);
            seg_attn<0><<<12500 * 5, 256, 0, stream>>>(
                permv, offsets, message, ts, nei1, nei2, msg_out, t_out, score);
        }

        softmax_partial<<<128, 256, 0, stream>>>(score, partials);
        k_norm<<<(B_BATCH * K_NEI + 255) / 256, 256, 0, stream>>>(score, partials);
    }
}

// Round 11
// 433.924 us; speedup vs baseline: 4.2422x; 1.0120x over previous
//
#include <hip/hip_runtime.h>

#define N_NODES 200000
#define E_EVENTS 1000000
#define D_DIM 128
#define B_BATCH 50000
#define K_NEI 20
#define NCHUNK 196            // ceil(200000/1024)
#define SLOTS_PER_NODE 32

// ---------------- ws layout A: slot path (needs ~52 MB) --------------------
#define WA_CURSOR   0         // int[200000]
#define WA_PARTIALS 200064    // float2[128*20] -> 5120 floats, ends 205184
#define WA_SLOTS    205440    // int2[200000*32] = 12.8M ints (8B aligned)

// ---------------- ws layout B: CSR fallback (R9-proven) --------------------
#define WB_COUNTS   0         // [200000]
#define WB_OFFSETS  200000    // [200000]
#define WB_CURSOR   400000    // [200000]
#define WB_CHUNK    600000    // [256]
#define WB_PARTIALS 600320    // float2[128*20] -> ends 605440
#define WB_PERM     605440    // int2[1M] (TSP=1) or int[1M] (TSP=0)

// ---------------------------------------------------------------------------
// attention logits for unit u (4 b's, one per wave) — verified R5/R8/R9/R10.
// ---------------------------------------------------------------------------
__device__ __forceinline__ void attn_unit(int u, int wid, int lane,
    const float* __restrict__ nei1, const float* __restrict__ nei2,
    float* __restrict__ logits)
{
    int b = u * 4 + wid;
    int c = lane & 31, h = lane >> 5;
    const float4* n2 = reinterpret_cast<const float4*>(nei2) + (size_t)b * (K_NEI * 32);
    float4 acc = make_float4(0.f, 0.f, 0.f, 0.f);
#pragma unroll
    for (int i = 0; i < K_NEI / 2; ++i) {
        float4 v = n2[(2 * i + h) * 32 + c];
        acc.x += v.x; acc.y += v.y; acc.z += v.z; acc.w += v.w;
    }
    float4 s4;
    s4.x = acc.x + __shfl_xor(acc.x, 32);
    s4.y = acc.y + __shfl_xor(acc.y, 32);
    s4.z = acc.z + __shfl_xor(acc.z, 32);
    s4.w = acc.w + __shfl_xor(acc.w, 32);

    const float4* n1 = reinterpret_cast<const float4*>(nei1) + (size_t)b * (K_NEI * 32);
    float p[K_NEI / 2];
#pragma unroll
    for (int i = 0; i < K_NEI / 2; ++i) {
        float4 v = n1[(2 * i + h) * 32 + c];
        float pp = v.x * s4.x + v.y * s4.y + v.z * s4.z + v.w * s4.w;
#pragma unroll
        for (int off = 16; off; off >>= 1) pp += __shfl_xor(pp, off);
        p[i] = pp;
    }
    int sel = c >> 1;
    float v = p[0];
#pragma unroll
    for (int i = 1; i < K_NEI / 2; ++i) v = (sel == i) ? p[i] : v;
    float vf = __shfl(v, ((lane & 1) << 5) + c);
    if (lane < K_NEI) logits[(size_t)b * K_NEI + lane] = vf;
}

// ---------------------------------------------------------------------------
// SLOT-path segment reduce: one wave per node.
// Common case (cnt<=8, ~93%): ONE 64 B slot line read, issued in parallel
// with the cnt load. Rare case (cnt>8): conditional read of slots 8..31,
// serialized on cnt but overlapped with the first rows' gathers.
// ---------------------------------------------------------------------------
__device__ __forceinline__ void seg_node_slots(int n, int lane,
    const int2* __restrict__ slots, const int* __restrict__ cursor,
    const float* __restrict__ message,
    float* __restrict__ msg_out, float* __restrict__ t_out)
{
    int c = lane & 31, h = lane >> 5;
    int cnt = cursor[n];                                    // wave-uniform
    int2 pe = slots[(size_t)n * SLOTS_PER_NODE + (c & 7)];  // 64 B, indep of cnt
    int cl = min(cnt, SLOTS_PER_NODE);
    if (cl > 8 && c >= 8 && c < cl)                         // rare (~7% of nodes)
        pe = slots[(size_t)n * SLOTS_PER_NODE + c];

    int   e_l = pe.x;
    float t_l = (c < cl) ? __int_as_float(pe.y) : 0.f;

    const float4* msg4 = reinterpret_cast<const float4*>(message);
    float4 acc0 = make_float4(0.f, 0.f, 0.f, 0.f);
    float4 acc1 = make_float4(0.f, 0.f, 0.f, 0.f);
    float tmax = t_l;                                       // dup halves: max-safe

    int i = 0;
    for (; i + 8 <= cl; i += 8) {
        int eA = __shfl(e_l, i + 0 + h);
        int eB = __shfl(e_l, i + 2 + h);
        int eC = __shfl(e_l, i + 4 + h);
        int eD = __shfl(e_l, i + 6 + h);
        float4 vA = msg4[(size_t)eA * 32 + c];
        float4 vB = msg4[(size_t)eB * 32 + c];
        float4 vC = msg4[(size_t)eC * 32 + c];
        float4 vD = msg4[(size_t)eD * 32 + c];
        acc0.x += vA.x; acc0.y += vA.y; acc0.z += vA.z; acc0.w += vA.w;
        acc1.x += vB.x; acc1.y += vB.y; acc1.z += vB.z; acc1.w += vB.w;
        acc0.x += vC.x; acc0.y += vC.y; acc0.z += vC.z; acc0.w += vC.w;
        acc1.x += vD.x; acc1.y += vD.y; acc1.z += vD.z; acc1.w += vD.w;
    }
    for (; i + 2 <= cl; i += 2) {
        int e = __shfl(e_l, i + h);
        float4 v = msg4[(size_t)e * 32 + c];
        acc0.x += v.x; acc0.y += v.y; acc0.z += v.z; acc0.w += v.w;
    }
    if (i < cl) {
        int e = __shfl(e_l, i);
        if (h == 0) {
            float4 v = msg4[(size_t)e * 32 + c];
            acc0.x += v.x; acc0.y += v.y; acc0.z += v.z; acc0.w += v.w;
        }
    }

    float4 acc = make_float4(acc0.x + acc1.x, acc0.y + acc1.y,
                             acc0.z + acc1.z, acc0.w + acc1.w);
    acc.x += __shfl_xor(acc.x, 32);
    acc.y += __shfl_xor(acc.y, 32);
    acc.z += __shfl_xor(acc.z, 32);
    acc.w += __shfl_xor(acc.w, 32);
    float inv = 1.0f / (float)max(cnt, 1);
    if (h == 0) {
        reinterpret_cast<float4*>(msg_out)[(size_t)n * 32 + c] =
            make_float4(acc.x * inv, acc.y * inv, acc.z * inv, acc.w * inv);
    }
#pragma unroll
    for (int off = 32; off; off >>= 1) tmax = fmaxf(tmax, __shfl_xor(tmax, off));
    if (lane == 0) t_out[n] = tmax;
}

// ---------------------------------------------------------------------------
// SLOT-path scatter: the entire CSR build in one kernel. 1 thread/event.
// ---------------------------------------------------------------------------
__global__ void k_scat_slots(const int* __restrict__ ids, const float* __restrict__ ts,
                             int* __restrict__ cursor, int2* __restrict__ slots)
{
    int e = blockIdx.x * blockDim.x + threadIdx.x;
    if (e < E_EVENTS) {
        int id = ids[e];
        int pos = atomicAdd(cursor + id, 1);
        if (pos < SLOTS_PER_NODE)
            slots[(size_t)id * SLOTS_PER_NODE + pos] = make_int2(e, __float_as_int(ts[e]));
    }
}

// ---------------------------------------------------------------------------
// SLOT-path fused seg+attn — R5's proven 5-block-group structure.
// ---------------------------------------------------------------------------
__global__ void __launch_bounds__(256, 8)
seg_attn_slots(const int2* __restrict__ slots, const int* __restrict__ cursor,
               const float* __restrict__ message,
               const float* __restrict__ nei1, const float* __restrict__ nei2,
               float* __restrict__ msg_out, float* __restrict__ t_out,
               float* __restrict__ logits)
{
    int g = blockIdx.x / 5, r = blockIdx.x % 5;
    int t = threadIdx.x;
    int wid = t >> 6, lane = t & 63;

    if (r < 4) {
        int n = (g * 4 + r) * 4 + wid;            // covers 200000 exactly
        seg_node_slots(n, lane, slots, cursor, message, msg_out, t_out);
    } else {
        attn_unit(g, wid, lane, nei1, nei2, logits);   // g in [0,12500)
    }
}

// ============================ CSR FALLBACK (R9) =============================
template<int TSP>
__device__ __forceinline__ void seg_node(int n, int lane,
    const void* __restrict__ permv, const int* __restrict__ offsets,
    const float* __restrict__ message, const float* __restrict__ ts,
    float* __restrict__ msg_out, float* __restrict__ t_out)
{
    int c = lane & 31, h = lane >> 5;
    int start = offsets[n];
    int end   = (n < N_NODES - 1) ? offsets[n + 1] : E_EVENTS;
    int len   = end - start;

    const float4* msg4 = reinterpret_cast<const float4*>(message);
    float4 acc0 = make_float4(0.f, 0.f, 0.f, 0.f);
    float4 acc1 = make_float4(0.f, 0.f, 0.f, 0.f);
    float tmax = 0.f;

    for (int base = start; base < end; base += 64) {
        int cl = min(end - base, 64);
        int e_l = 0; float t_l = 0.f;
        if (lane < cl) {
            if (TSP) {
                int2 pe = ((const int2*)permv)[base + lane];
                e_l = pe.x; t_l = __int_as_float(pe.y);
            } else {
                e_l = ((const int*)permv)[base + lane];
                t_l = ts[e_l];
            }
        }
        tmax = fmaxf(tmax, t_l);
        int i = 0;
        for (; i + 8 <= cl; i += 8) {
            int eA = __shfl(e_l, i + 0 + h);
            int eB = __shfl(e_l, i + 2 + h);
            int eC = __shfl(e_l, i + 4 + h);
            int eD = __shfl(e_l, i + 6 + h);
            float4 vA = msg4[(size_t)eA * 32 + c];
            float4 vB = msg4[(size_t)eB * 32 + c];
            float4 vC = msg4[(size_t)eC * 32 + c];
            float4 vD = msg4[(size_t)eD * 32 + c];
            acc0.x += vA.x; acc0.y += vA.y; acc0.z += vA.z; acc0.w += vA.w;
            acc1.x += vB.x; acc1.y += vB.y; acc1.z += vB.z; acc1.w += vB.w;
            acc0.x += vC.x; acc0.y += vC.y; acc0.z += vC.z; acc0.w += vC.w;
            acc1.x += vD.x; acc1.y += vD.y; acc1.z += vD.z; acc1.w += vD.w;
        }
        for (; i + 2 <= cl; i += 2) {
            int e = __shfl(e_l, i + h);
            float4 v = msg4[(size_t)e * 32 + c];
            acc0.x += v.x; acc0.y += v.y; acc0.z += v.z; acc0.w += v.w;
        }
        if (i < cl) {
            int e = __shfl(e_l, i);
            if (h == 0) {
                float4 v = msg4[(size_t)e * 32 + c];
                acc0.x += v.x; acc0.y += v.y; acc0.z += v.z; acc0.w += v.w;
            }
        }
    }
    float4 acc = make_float4(acc0.x + acc1.x, acc0.y + acc1.y,
                             acc0.z + acc1.z, acc0.w + acc1.w);
    acc.x += __shfl_xor(acc.x, 32);
    acc.y += __shfl_xor(acc.y, 32);
    acc.z += __shfl_xor(acc.z, 32);
    acc.w += __shfl_xor(acc.w, 32);
    float inv = 1.0f / (float)max(len, 1);
    if (h == 0) {
        reinterpret_cast<float4*>(msg_out)[(size_t)n * 32 + c] =
            make_float4(acc.x * inv, acc.y * inv, acc.z * inv, acc.w * inv);
    }
#pragma unroll
    for (int off = 32; off; off >>= 1) tmax = fmaxf(tmax, __shfl_xor(tmax, off));
    if (lane == 0) t_out[n] = tmax;
}

__global__ void k_hist(const int* __restrict__ ids, int* __restrict__ counts)
{
    int e = blockIdx.x * blockDim.x + threadIdx.x;
    if (e < E_EVENTS) atomicAdd(counts + ids[e], 1);
}

__global__ void __launch_bounds__(256)
k_scanb(const int* __restrict__ counts, int* __restrict__ chunkSums)
{
    __shared__ int sd[256];
    int t = threadIdx.x, base = blockIdx.x * 1024 + t * 4;
    int s = 0;
#pragma unroll
    for (int j = 0; j < 4; ++j) { int i = base + j; if (i < N_NODES) s += counts[i]; }
    sd[t] = s; __syncthreads();
    for (int off = 128; off; off >>= 1) {
        if (t < off) sd[t] += sd[t + off];
        __syncthreads();
    }
    if (t == 0) chunkSums[blockIdx.x] = sd[0];
}

__global__ void __launch_bounds__(256)
k_scanf(const int* __restrict__ counts, const int* __restrict__ chunkSums,
        int* __restrict__ offsets, int* __restrict__ cursor)
{
    __shared__ int sd[256];
    int bid = blockIdx.x, t = threadIdx.x;
    int v = (t < NCHUNK) ? chunkSums[t] : 0;
    sd[t] = v; __syncthreads();
    for (int off = 1; off < 256; off <<= 1) {
        int x = (t >= off) ? sd[t - off] : 0;
        __syncthreads();
        sd[t] += x;
        __syncthreads();
    }
    int chunkBase = (bid == 0) ? 0 : sd[bid - 1];
    __syncthreads();
    int base = bid * 1024 + t * 4;
    int c0 = (base + 0 < N_NODES) ? counts[base + 0] : 0;
    int c1 = (base + 1 < N_NODES) ? counts[base + 1] : 0;
    int c2 = (base + 2 < N_NODES) ? counts[base + 2] : 0;
    int c3 = (base + 3 < N_NODES) ? counts[base + 3] : 0;
    int tsum = c0 + c1 + c2 + c3;
    sd[t] = tsum; __syncthreads();
    for (int off = 1; off < 256; off <<= 1) {
        int x = (t >= off) ? sd[t - off] : 0;
        __syncthreads();
        sd[t] += x;
        __syncthreads();
    }
    int excl = sd[t] - tsum + chunkBase;
    if (base + 0 < N_NODES) { offsets[base + 0] = excl; cursor[base + 0] = excl; } excl += c0;
    if (base + 1 < N_NODES) { offsets[base + 1] = excl; cursor[base + 1] = excl; } excl += c1;
    if (base + 2 < N_NODES) { offsets[base + 2] = excl; cursor[base + 2] = excl; } excl += c2;
    if (base + 3 < N_NODES) { offsets[base + 3] = excl; cursor[base + 3] = excl; } excl += c3;
}

template<int TSP>
__global__ void k_scat(const int* __restrict__ ids, const float* __restrict__ ts,
                       int* __restrict__ cursor, void* __restrict__ permv)
{
    int e = blockIdx.x * blockDim.x + threadIdx.x;
    if (e < E_EVENTS) {
        int pos = atomicAdd(cursor + ids[e], 1);
        if (TSP) ((int2*)permv)[pos] = make_int2(e, __float_as_int(ts[e]));
        else     ((int*)permv)[pos]  = e;
    }
}

template<int TSP>
__global__ void __launch_bounds__(256, 8)
seg_attn(const void* __restrict__ permv, const int* __restrict__ offsets,
         const float* __restrict__ message, const float* __restrict__ ts,
         const float* __restrict__ nei1, const float* __restrict__ nei2,
         float* __restrict__ msg_out, float* __restrict__ t_out,
         float* __restrict__ logits)
{
    int g = blockIdx.x / 5, r = blockIdx.x % 5;
    int t = threadIdx.x;
    int wid = t >> 6, lane = t & 63;

    if (r < 4) {
        int n = (g * 4 + r) * 4 + wid;
        seg_node<TSP>(n, lane, permv, offsets, message, ts, msg_out, t_out);
    } else {
        attn_unit(g, wid, lane, nei1, nei2, logits);
    }
}
// ========================== end CSR fallback ================================

// ---------------------------------------------------------------------------
// softmax tail (shared): per-block partials + redundant-stats normalize.
// ---------------------------------------------------------------------------
__global__ void softmax_partial(const float* __restrict__ logits, float2* __restrict__ partials)
{
    int t = threadIdx.x;
    float m[K_NEI], s[K_NEI];
#pragma unroll
    for (int k = 0; k < K_NEI; ++k) { m[k] = -INFINITY; s[k] = 0.f; }

    for (int b = blockIdx.x * 256 + t; b < B_BATCH; b += 128 * 256) {
        const float4* row = reinterpret_cast<const float4*>(logits + (size_t)b * K_NEI);
        float v[K_NEI];
#pragma unroll
        for (int q = 0; q < 5; ++q) {
            float4 rr = row[q];
            v[q * 4 + 0] = rr.x; v[q * 4 + 1] = rr.y; v[q * 4 + 2] = rr.z; v[q * 4 + 3] = rr.w;
        }
#pragma unroll
        for (int k = 0; k < K_NEI; ++k) {
            float nm = fmaxf(m[k], v[k]);
            s[k] = s[k] * expf(m[k] - nm) + expf(v[k] - nm);
            m[k] = nm;
        }
    }
#pragma unroll
    for (int k = 0; k < K_NEI; ++k) {
#pragma unroll
        for (int off = 32; off; off >>= 1) {
            float om = __shfl_xor(m[k], off);
            float os = __shfl_xor(s[k], off);
            float nm = fmaxf(m[k], om);
            s[k] = s[k] * expf(m[k] - nm) + os * expf(om - nm);
            m[k] = nm;
        }
    }
    __shared__ float lm[4][K_NEI], lsum[4][K_NEI];
    int wid = t >> 6, lane = t & 63;
    if (lane == 0) {
#pragma unroll
        for (int k = 0; k < K_NEI; ++k) { lm[wid][k] = m[k]; lsum[wid][k] = s[k]; }
    }
    __syncthreads();
    if (t < K_NEI) {
        float mm = lm[0][t], ss = lsum[0][t];
#pragma unroll
        for (int w = 1; w < 4; ++w) {
            float om = lm[w][t], os = lsum[w][t];
            float nm = fmaxf(mm, om);
            ss = ss * expf(mm - nm) + os * expf(om - nm);
            mm = nm;
        }
        partials[blockIdx.x * K_NEI + t] = make_float2(mm, ss);
    }
}

__global__ void __launch_bounds__(256)
k_norm(float* __restrict__ score, const float2* __restrict__ partials)
{
    __shared__ float sm[256], ssum[256];
    __shared__ float stm[K_NEI], sinv[K_NEI];
    int t = threadIdx.x;
    float m = -INFINITY, s = 0.f;
    if (t < 240) {
        int k = t % K_NEI, g = t / K_NEI;
        int j0 = g * 11, j1 = min(j0 + 11, 128);
        for (int j = j0; j < j1; ++j) {
            float2 p = partials[j * K_NEI + k];
            float nm = fmaxf(m, p.x);
            s = s * expf(m - nm) + p.y * expf(p.x - nm);
            m = nm;
        }
    }
    sm[t] = m; ssum[t] = s; __syncthreads();
    if (t < K_NEI) {
        float mm = -INFINITY, ss = 0.f;
#pragma unroll
        for (int g = 0; g < 12; ++g) {
            float pm = sm[g * K_NEI + t], ps = ssum[g * K_NEI + t];
            float nm = fmaxf(mm, pm);
            ss = ss * expf(mm - nm) + ps * expf(pm - nm);
            mm = nm;
        }
        stm[t] = mm; sinv[t] = 1.0f / ss;
    }
    __syncthreads();
    int i = blockIdx.x * 256 + t;
    if (i < B_BATCH * K_NEI) {
        int k = i % K_NEI;
        score[i] = expf(score[i] - stm[k]) * sinv[k];
    }
}

extern "C" void kernel_launch(void* const* d_in, const int* in_sizes, int n_in,
                              void* d_out, int out_size, void* d_ws, size_t ws_size,
                              hipStream_t stream)
{
    const int*   node_ids = (const int*)  d_in[0];
    const float* message  = (const float*)d_in[1];
    const float* ts       = (const float*)d_in[2];
    const float* nei1     = (const float*)d_in[3];
    const float* nei2     = (const float*)d_in[4];

    float* out     = (float*)d_out;
    float* msg_out = out;                                   // [N,128]
    float* t_out   = out + (size_t)N_NODES * D_DIM;         // [N]
    float* score   = t_out + N_NODES;                       // [B,K]

    int* wsi = (int*)d_ws;

    size_t slots_need = ((size_t)WA_SLOTS + 2u * (size_t)N_NODES * SLOTS_PER_NODE) * sizeof(int);

    if (ws_size >= slots_need) {
        int*    cursor   = wsi + WA_CURSOR;
        float2* partials = (float2*)(wsi + WA_PARTIALS);
        int2*   slots    = (int2*)(wsi + WA_SLOTS);

        hipMemsetAsync(cursor, 0, (size_t)N_NODES * sizeof(int), stream);

        k_scat_slots<<<(E_EVENTS + 255) / 256, 256, 0, stream>>>(node_ids, ts, cursor, slots);
        seg_attn_slots<<<12500 * 5, 256, 0, stream>>>(
            slots, cursor, message, nei1, nei2, msg_out, t_out, score);
        softmax_partial<<<128, 256, 0, stream>>>(score, partials);
        k_norm<<<(B_BATCH * K_NEI + 255) / 256, 256, 0, stream>>>(score, partials);
    } else {
        // -------- CSR fallback (R9-proven) ----------------------------------
        int*    counts    = wsi + WB_COUNTS;
        int*    offsets   = wsi + WB_OFFSETS;
        int*    cursor    = wsi + WB_CURSOR;
        int*    chunkSums = wsi + WB_CHUNK;
        float2* partials  = (float2*)(wsi + WB_PARTIALS);
        void*   permv     = (void*)(wsi + WB_PERM);

        bool tsp = ws_size >= ((size_t)WB_PERM + 2u * E_EVENTS) * sizeof(int);

        hipMemsetAsync(counts, 0, (size_t)N_NODES * sizeof(int), stream);

        k_hist<<<(E_EVENTS + 255) / 256, 256, 0, stream>>>(node_ids, counts);
        k_scanb<<<NCHUNK, 256, 0, stream>>>(counts, chunkSums);
        k_scanf<<<NCHUNK, 256, 0, stream>>>(counts, chunkSums, offsets, cursor);

        if (tsp) {
            k_scat<1><<<(E_EVENTS + 255) / 256, 256, 0, stream>>>(node_ids, ts, cursor, permv);
            seg_attn<1><<<12500 * 5, 256, 0, stream>>>(
                permv, offsets, message, ts, nei1, nei2, msg_out, t_out, score);
        } else {
            k_scat<0><<<(E_EVENTS + 255) / 256, 256, 0, stream>>>(node_ids, ts, cursor, permv);
            seg_attn<0><<<12500 * 5, 256, 0, stream>>>(
                permv, offsets, message, ts, nei1, nei2, msg_out, t_out, score);
        }

        softmax_partial<<<128, 256, 0, stream>>>(score, partials);
        k_norm<<<(B_BATCH * K_NEI + 255) / 256, 256, 0, stream>>>(score, partials);
    }
}

// Round 12
// 426.746 us; speedup vs baseline: 4.3136x; 1.0168x over previous
//
#include <hip/hip_runtime.h>

#define N_NODES 200000
#define E_EVENTS 1000000
#define D_DIM 128
#define B_BATCH 50000
#define K_NEI 20
#define NCHUNK 196            // ceil(200000/1024)
#define PRIM_SLOTS 8          // compact primary slots/node (12.8 MB, L2-resident)
#define OVER_SLOTS 24         // overflow slots/node (total cap 32, same as R10/R11)

// ---------------- ws layout A: two-level slot path (52.02 MB) --------------
#define WA_CURSOR   0         // int[200000]
#define WA_PARTIALS 200064    // float2[128*20] -> ends 205184 (pad to 205440)
#define WA_PRIM     205440    // int2[200000*8]  -> ends 3405440
#define WA_OVER     3405440   // int2[200000*24] -> ends 13005440

// ---------------- ws layout B: CSR fallback (R9-proven) --------------------
#define WB_COUNTS   0         // [200000]
#define WB_OFFSETS  200000    // [200000]
#define WB_CURSOR   400000    // [200000]
#define WB_CHUNK    600000    // [256]
#define WB_PARTIALS 600320    // float2[128*20] -> ends 605440
#define WB_PERM     605440    // int2[1M] (TSP=1) or int[1M] (TSP=0)

// ---------------------------------------------------------------------------
// attention logits for unit u (4 b's, one per wave) — verified R5..R11.
// ---------------------------------------------------------------------------
__device__ __forceinline__ void attn_unit(int u, int wid, int lane,
    const float* __restrict__ nei1, const float* __restrict__ nei2,
    float* __restrict__ logits)
{
    int b = u * 4 + wid;
    int c = lane & 31, h = lane >> 5;
    const float4* n2 = reinterpret_cast<const float4*>(nei2) + (size_t)b * (K_NEI * 32);
    float4 acc = make_float4(0.f, 0.f, 0.f, 0.f);
#pragma unroll
    for (int i = 0; i < K_NEI / 2; ++i) {
        float4 v = n2[(2 * i + h) * 32 + c];
        acc.x += v.x; acc.y += v.y; acc.z += v.z; acc.w += v.w;
    }
    float4 s4;
    s4.x = acc.x + __shfl_xor(acc.x, 32);
    s4.y = acc.y + __shfl_xor(acc.y, 32);
    s4.z = acc.z + __shfl_xor(acc.z, 32);
    s4.w = acc.w + __shfl_xor(acc.w, 32);

    const float4* n1 = reinterpret_cast<const float4*>(nei1) + (size_t)b * (K_NEI * 32);
    float p[K_NEI / 2];
#pragma unroll
    for (int i = 0; i < K_NEI / 2; ++i) {
        float4 v = n1[(2 * i + h) * 32 + c];
        float pp = v.x * s4.x + v.y * s4.y + v.z * s4.z + v.w * s4.w;
#pragma unroll
        for (int off = 16; off; off >>= 1) pp += __shfl_xor(pp, off);
        p[i] = pp;
    }
    int sel = c >> 1;
    float v = p[0];
#pragma unroll
    for (int i = 1; i < K_NEI / 2; ++i) v = (sel == i) ? p[i] : v;
    float vf = __shfl(v, ((lane & 1) << 5) + c);
    if (lane < K_NEI) logits[(size_t)b * K_NEI + lane] = vf;
}

// ---------------------------------------------------------------------------
// two-level slot segment reduce: one wave per node.
// Primary read = 64 B from the COMPACT 12.8 MB region (L2-hot after scatter),
// issued in parallel with the cnt load. Overflow (cnt>8, ~7%): conditional
// read from the separate overflow region.
// ---------------------------------------------------------------------------
__device__ __forceinline__ void seg_node_slots(int n, int lane,
    const int2* __restrict__ prim, const int2* __restrict__ over,
    const int* __restrict__ cursor, const float* __restrict__ message,
    float* __restrict__ msg_out, float* __restrict__ t_out)
{
    int c = lane & 31, h = lane >> 5;
    int cnt = cursor[n];                                    // wave-uniform
    int2 pe = prim[(size_t)n * PRIM_SLOTS + (c & 7)];       // 64 B, indep of cnt
    int cl = min(cnt, PRIM_SLOTS + OVER_SLOTS);
    if (cl > PRIM_SLOTS && c >= PRIM_SLOTS && c < cl)       // rare (~7% of nodes)
        pe = over[(size_t)n * OVER_SLOTS + (c - PRIM_SLOTS)];

    int   e_l = pe.x;
    float t_l = (c < cl) ? __int_as_float(pe.y) : 0.f;

    const float4* msg4 = reinterpret_cast<const float4*>(message);
    float4 acc0 = make_float4(0.f, 0.f, 0.f, 0.f);
    float4 acc1 = make_float4(0.f, 0.f, 0.f, 0.f);
    float tmax = t_l;                                       // dup halves: max-safe

    int i = 0;
    for (; i + 8 <= cl; i += 8) {
        int eA = __shfl(e_l, i + 0 + h);
        int eB = __shfl(e_l, i + 2 + h);
        int eC = __shfl(e_l, i + 4 + h);
        int eD = __shfl(e_l, i + 6 + h);
        float4 vA = msg4[(size_t)eA * 32 + c];
        float4 vB = msg4[(size_t)eB * 32 + c];
        float4 vC = msg4[(size_t)eC * 32 + c];
        float4 vD = msg4[(size_t)eD * 32 + c];
        acc0.x += vA.x; acc0.y += vA.y; acc0.z += vA.z; acc0.w += vA.w;
        acc1.x += vB.x; acc1.y += vB.y; acc1.z += vB.z; acc1.w += vB.w;
        acc0.x += vC.x; acc0.y += vC.y; acc0.z += vC.z; acc0.w += vC.w;
        acc1.x += vD.x; acc1.y += vD.y; acc1.z += vD.z; acc1.w += vD.w;
    }
    for (; i + 2 <= cl; i += 2) {
        int e = __shfl(e_l, i + h);
        float4 v = msg4[(size_t)e * 32 + c];
        acc0.x += v.x; acc0.y += v.y; acc0.z += v.z; acc0.w += v.w;
    }
    if (i < cl) {
        int e = __shfl(e_l, i);
        if (h == 0) {
            float4 v = msg4[(size_t)e * 32 + c];
            acc0.x += v.x; acc0.y += v.y; acc0.z += v.z; acc0.w += v.w;
        }
    }

    float4 acc = make_float4(acc0.x + acc1.x, acc0.y + acc1.y,
                             acc0.z + acc1.z, acc0.w + acc1.w);
    acc.x += __shfl_xor(acc.x, 32);
    acc.y += __shfl_xor(acc.y, 32);
    acc.z += __shfl_xor(acc.z, 32);
    acc.w += __shfl_xor(acc.w, 32);
    float inv = 1.0f / (float)max(cnt, 1);
    if (h == 0) {
        reinterpret_cast<float4*>(msg_out)[(size_t)n * 32 + c] =
            make_float4(acc.x * inv, acc.y * inv, acc.z * inv, acc.w * inv);
    }
#pragma unroll
    for (int off = 32; off; off >>= 1) tmax = fmaxf(tmax, __shfl_xor(tmax, off));
    if (lane == 0) t_out[n] = tmax;
}

// ---------------------------------------------------------------------------
// two-level slot scatter: the entire CSR build in one kernel. 1 thread/event.
// ---------------------------------------------------------------------------
__global__ void k_scat_slots(const int* __restrict__ ids, const float* __restrict__ ts,
                             int* __restrict__ cursor,
                             int2* __restrict__ prim, int2* __restrict__ over)
{
    int e = blockIdx.x * blockDim.x + threadIdx.x;
    if (e < E_EVENTS) {
        int id = ids[e];
        int pos = atomicAdd(cursor + id, 1);
        int2 rec = make_int2(e, __float_as_int(ts[e]));
        if (pos < PRIM_SLOTS)
            prim[(size_t)id * PRIM_SLOTS + pos] = rec;
        else if (pos < PRIM_SLOTS + OVER_SLOTS)
            over[(size_t)id * OVER_SLOTS + (pos - PRIM_SLOTS)] = rec;
    }
}

// ---------------------------------------------------------------------------
// slot-path fused seg+attn — R5's proven 5-block-group structure.
// ---------------------------------------------------------------------------
__global__ void __launch_bounds__(256, 8)
seg_attn_slots(const int2* __restrict__ prim, const int2* __restrict__ over,
               const int* __restrict__ cursor, const float* __restrict__ message,
               const float* __restrict__ nei1, const float* __restrict__ nei2,
               float* __restrict__ msg_out, float* __restrict__ t_out,
               float* __restrict__ logits)
{
    int g = blockIdx.x / 5, r = blockIdx.x % 5;
    int t = threadIdx.x;
    int wid = t >> 6, lane = t & 63;

    if (r < 4) {
        int n = (g * 4 + r) * 4 + wid;            // covers 200000 exactly
        seg_node_slots(n, lane, prim, over, cursor, message, msg_out, t_out);
    } else {
        attn_unit(g, wid, lane, nei1, nei2, logits);   // g in [0,12500)
    }
}

// ============================ CSR FALLBACK (R9) =============================
template<int TSP>
__device__ __forceinline__ void seg_node(int n, int lane,
    const void* __restrict__ permv, const int* __restrict__ offsets,
    const float* __restrict__ message, const float* __restrict__ ts,
    float* __restrict__ msg_out, float* __restrict__ t_out)
{
    int c = lane & 31, h = lane >> 5;
    int start = offsets[n];
    int end   = (n < N_NODES - 1) ? offsets[n + 1] : E_EVENTS;
    int len   = end - start;

    const float4* msg4 = reinterpret_cast<const float4*>(message);
    float4 acc0 = make_float4(0.f, 0.f, 0.f, 0.f);
    float4 acc1 = make_float4(0.f, 0.f, 0.f, 0.f);
    float tmax = 0.f;

    for (int base = start; base < end; base += 64) {
        int cl = min(end - base, 64);
        int e_l = 0; float t_l = 0.f;
        if (lane < cl) {
            if (TSP) {
                int2 pe = ((const int2*)permv)[base + lane];
                e_l = pe.x; t_l = __int_as_float(pe.y);
            } else {
                e_l = ((const int*)permv)[base + lane];
                t_l = ts[e_l];
            }
        }
        tmax = fmaxf(tmax, t_l);
        int i = 0;
        for (; i + 8 <= cl; i += 8) {
            int eA = __shfl(e_l, i + 0 + h);
            int eB = __shfl(e_l, i + 2 + h);
            int eC = __shfl(e_l, i + 4 + h);
            int eD = __shfl(e_l, i + 6 + h);
            float4 vA = msg4[(size_t)eA * 32 + c];
            float4 vB = msg4[(size_t)eB * 32 + c];
            float4 vC = msg4[(size_t)eC * 32 + c];
            float4 vD = msg4[(size_t)eD * 32 + c];
            acc0.x += vA.x; acc0.y += vA.y; acc0.z += vA.z; acc0.w += vA.w;
            acc1.x += vB.x; acc1.y += vB.y; acc1.z += vB.z; acc1.w += vB.w;
            acc0.x += vC.x; acc0.y += vC.y; acc0.z += vC.z; acc0.w += vC.w;
            acc1.x += vD.x; acc1.y += vD.y; acc1.z += vD.z; acc1.w += vD.w;
        }
        for (; i + 2 <= cl; i += 2) {
            int e = __shfl(e_l, i + h);
            float4 v = msg4[(size_t)e * 32 + c];
            acc0.x += v.x; acc0.y += v.y; acc0.z += v.z; acc0.w += v.w;
        }
        if (i < cl) {
            int e = __shfl(e_l, i);
            if (h == 0) {
                float4 v = msg4[(size_t)e * 32 + c];
                acc0.x += v.x; acc0.y += v.y; acc0.z += v.z; acc0.w += v.w;
            }
        }
    }
    float4 acc = make_float4(acc0.x + acc1.x, acc0.y + acc1.y,
                             acc0.z + acc1.z, acc0.w + acc1.w);
    acc.x += __shfl_xor(acc.x, 32);
    acc.y += __shfl_xor(acc.y, 32);
    acc.z += __shfl_xor(acc.z, 32);
    acc.w += __shfl_xor(acc.w, 32);
    float inv = 1.0f / (float)max(len, 1);
    if (h == 0) {
        reinterpret_cast<float4*>(msg_out)[(size_t)n * 32 + c] =
            make_float4(acc.x * inv, acc.y * inv, acc.z * inv, acc.w * inv);
    }
#pragma unroll
    for (int off = 32; off; off >>= 1) tmax = fmaxf(tmax, __shfl_xor(tmax, off));
    if (lane == 0) t_out[n] = tmax;
}

__global__ void k_hist(const int* __restrict__ ids, int* __restrict__ counts)
{
    int e = blockIdx.x * blockDim.x + threadIdx.x;
    if (e < E_EVENTS) atomicAdd(counts + ids[e], 1);
}

__global__ void __launch_bounds__(256)
k_scanb(const int* __restrict__ counts, int* __restrict__ chunkSums)
{
    __shared__ int sd[256];
    int t = threadIdx.x, base = blockIdx.x * 1024 + t * 4;
    int s = 0;
#pragma unroll
    for (int j = 0; j < 4; ++j) { int i = base + j; if (i < N_NODES) s += counts[i]; }
    sd[t] = s; __syncthreads();
    for (int off = 128; off; off >>= 1) {
        if (t < off) sd[t] += sd[t + off];
        __syncthreads();
    }
    if (t == 0) chunkSums[blockIdx.x] = sd[0];
}

__global__ void __launch_bounds__(256)
k_scanf(const int* __restrict__ counts, const int* __restrict__ chunkSums,
        int* __restrict__ offsets, int* __restrict__ cursor)
{
    __shared__ int sd[256];
    int bid = blockIdx.x, t = threadIdx.x;
    int v = (t < NCHUNK) ? chunkSums[t] : 0;
    sd[t] = v; __syncthreads();
    for (int off = 1; off < 256; off <<= 1) {
        int x = (t >= off) ? sd[t - off] : 0;
        __syncthreads();
        sd[t] += x;
        __syncthreads();
    }
    int chunkBase = (bid == 0) ? 0 : sd[bid - 1];
    __syncthreads();
    int base = bid * 1024 + t * 4;
    int c0 = (base + 0 < N_NODES) ? counts[base + 0] : 0;
    int c1 = (base + 1 < N_NODES) ? counts[base + 1] : 0;
    int c2 = (base + 2 < N_NODES) ? counts[base + 2] : 0;
    int c3 = (base + 3 < N_NODES) ? counts[base + 3] : 0;
    int tsum = c0 + c1 + c2 + c3;
    sd[t] = tsum; __syncthreads();
    for (int off = 1; off < 256; off <<= 1) {
        int x = (t >= off) ? sd[t - off] : 0;
        __syncthreads();
        sd[t] += x;
        __syncthreads();
    }
    int excl = sd[t] - tsum + chunkBase;
    if (base + 0 < N_NODES) { offsets[base + 0] = excl; cursor[base + 0] = excl; } excl += c0;
    if (base + 1 < N_NODES) { offsets[base + 1] = excl; cursor[base + 1] = excl; } excl += c1;
    if (base + 2 < N_NODES) { offsets[base + 2] = excl; cursor[base + 2] = excl; } excl += c2;
    if (base + 3 < N_NODES) { offsets[base + 3] = excl; cursor[base + 3] = excl; } excl += c3;
}

template<int TSP>
__global__ void k_scat(const int* __restrict__ ids, const float* __restrict__ ts,
                       int* __restrict__ cursor, void* __restrict__ permv)
{
    int e = blockIdx.x * blockDim.x + threadIdx.x;
    if (e < E_EVENTS) {
        int pos = atomicAdd(cursor + ids[e], 1);
        if (TSP) ((int2*)permv)[pos] = make_int2(e, __float_as_int(ts[e]));
        else     ((int*)permv)[pos]  = e;
    }
}

template<int TSP>
__global__ void __launch_bounds__(256, 8)
seg_attn(const void* __restrict__ permv, const int* __restrict__ offsets,
         const float* __restrict__ message, const float* __restrict__ ts,
         const float* __restrict__ nei1, const float* __restrict__ nei2,
         float* __restrict__ msg_out, float* __restrict__ t_out,
         float* __restrict__ logits)
{
    int g = blockIdx.x / 5, r = blockIdx.x % 5;
    int t = threadIdx.x;
    int wid = t >> 6, lane = t & 63;

    if (r < 4) {
        int n = (g * 4 + r) * 4 + wid;
        seg_node<TSP>(n, lane, permv, offsets, message, ts, msg_out, t_out);
    } else {
        attn_unit(g, wid, lane, nei1, nei2, logits);
    }
}
// ========================== end CSR fallback ================================

// ---------------------------------------------------------------------------
// softmax tail (shared): per-block partials + redundant-stats normalize.
// ---------------------------------------------------------------------------
__global__ void softmax_partial(const float* __restrict__ logits, float2* __restrict__ partials)
{
    int t = threadIdx.x;
    float m[K_NEI], s[K_NEI];
#pragma unroll
    for (int k = 0; k < K_NEI; ++k) { m[k] = -INFINITY; s[k] = 0.f; }

    for (int b = blockIdx.x * 256 + t; b < B_BATCH; b += 128 * 256) {
        const float4* row = reinterpret_cast<const float4*>(logits + (size_t)b * K_NEI);
        float v[K_NEI];
#pragma unroll
        for (int q = 0; q < 5; ++q) {
            float4 rr = row[q];
            v[q * 4 + 0] = rr.x; v[q * 4 + 1] = rr.y; v[q * 4 + 2] = rr.z; v[q * 4 + 3] = rr.w;
        }
#pragma unroll
        for (int k = 0; k < K_NEI; ++k) {
            float nm = fmaxf(m[k], v[k]);
            s[k] = s[k] * expf(m[k] - nm) + expf(v[k] - nm);
            m[k] = nm;
        }
    }
#pragma unroll
    for (int k = 0; k < K_NEI; ++k) {
#pragma unroll
        for (int off = 32; off; off >>= 1) {
            float om = __shfl_xor(m[k], off);
            float os = __shfl_xor(s[k], off);
            float nm = fmaxf(m[k], om);
            s[k] = s[k] * expf(m[k] - nm) + os * expf(om - nm);
            m[k] = nm;
        }
    }
    __shared__ float lm[4][K_NEI], lsum[4][K_NEI];
    int wid = t >> 6, lane = t & 63;
    if (lane == 0) {
#pragma unroll
        for (int k = 0; k < K_NEI; ++k) { lm[wid][k] = m[k]; lsum[wid][k] = s[k]; }
    }
    __syncthreads();
    if (t < K_NEI) {
        float mm = lm[0][t], ss = lsum[0][t];
#pragma unroll
        for (int w = 1; w < 4; ++w) {
            float om = lm[w][t], os = lsum[w][t];
            float nm = fmaxf(mm, om);
            ss = ss * expf(mm - nm) + os * expf(om - nm);
            mm = nm;
        }
        partials[blockIdx.x * K_NEI + t] = make_float2(mm, ss);
    }
}

__global__ void __launch_bounds__(256)
k_norm(float* __restrict__ score, const float2* __restrict__ partials)
{
    __shared__ float sm[256], ssum[256];
    __shared__ float stm[K_NEI], sinv[K_NEI];
    int t = threadIdx.x;
    float m = -INFINITY, s = 0.f;
    if (t < 240) {
        int k = t % K_NEI, g = t / K_NEI;
        int j0 = g * 11, j1 = min(j0 + 11, 128);
        for (int j = j0; j < j1; ++j) {
            float2 p = partials[j * K_NEI + k];
            float nm = fmaxf(m, p.x);
            s = s * expf(m - nm) + p.y * expf(p.x - nm);
            m = nm;
        }
    }
    sm[t] = m; ssum[t] = s; __syncthreads();
    if (t < K_NEI) {
        float mm = -INFINITY, ss = 0.f;
#pragma unroll
        for (int g = 0; g < 12; ++g) {
            float pm = sm[g * K_NEI + t], ps = ssum[g * K_NEI + t];
            float nm = fmaxf(mm, pm);
            ss = ss * expf(mm - nm) + ps * expf(pm - nm);
            mm = nm;
        }
        stm[t] = mm; sinv[t] = 1.0f / ss;
    }
    __syncthreads();
    int i = blockIdx.x * 256 + t;
    if (i < B_BATCH * K_NEI) {
        int k = i % K_NEI;
        score[i] = expf(score[i] - stm[k]) * sinv[k];
    }
}

extern "C" void kernel_launch(void* const* d_in, const int* in_sizes, int n_in,
                              void* d_out, int out_size, void* d_ws, size_t ws_size,
                              hipStream_t stream)
{
    const int*   node_ids = (const int*)  d_in[0];
    const float* message  = (const float*)d_in[1];
    const float* ts       = (const float*)d_in[2];
    const float* nei1     = (const float*)d_in[3];
    const float* nei2     = (const float*)d_in[4];

    float* out     = (float*)d_out;
    float* msg_out = out;                                   // [N,128]
    float* t_out   = out + (size_t)N_NODES * D_DIM;         // [N]
    float* score   = t_out + N_NODES;                       // [B,K]

    int* wsi = (int*)d_ws;

    // two-level slot path: cursor + partials + prim(8/node) + over(24/node)
    size_t slots_need = ((size_t)WA_OVER + 2u * (size_t)N_NODES * OVER_SLOTS) * sizeof(int);

    if (ws_size >= slots_need) {
        int*    cursor   = wsi + WA_CURSOR;
        float2* partials = (float2*)(wsi + WA_PARTIALS);
        int2*   prim     = (int2*)(wsi + WA_PRIM);
        int2*   over     = (int2*)(wsi + WA_OVER);

        hipMemsetAsync(cursor, 0, (size_t)N_NODES * sizeof(int), stream);

        k_scat_slots<<<(E_EVENTS + 255) / 256, 256, 0, stream>>>(
            node_ids, ts, cursor, prim, over);
        seg_attn_slots<<<12500 * 5, 256, 0, stream>>>(
            prim, over, cursor, message, nei1, nei2, msg_out, t_out, score);
        softmax_partial<<<128, 256, 0, stream>>>(score, partials);
        k_norm<<<(B_BATCH * K_NEI + 255) / 256, 256, 0, stream>>>(score, partials);
    } else {
        // -------- CSR fallback (R9-proven) ----------------------------------
        int*    counts    = wsi + WB_COUNTS;
        int*    offsets   = wsi + WB_OFFSETS;
        int*    cursor    = wsi + WB_CURSOR;
        int*    chunkSums = wsi + WB_CHUNK;
        float2* partials  = (float2*)(wsi + WB_PARTIALS);
        void*   permv     = (void*)(wsi + WB_PERM);

        bool tsp = ws_size >= ((size_t)WB_PERM + 2u * E_EVENTS) * sizeof(int);

        hipMemsetAsync(counts, 0, (size_t)N_NODES * sizeof(int), stream);

        k_hist<<<(E_EVENTS + 255) / 256, 256, 0, stream>>>(node_ids, counts);
        k_scanb<<<NCHUNK, 256, 0, stream>>>(counts, chunkSums);
        k_scanf<<<NCHUNK, 256, 0, stream>>>(counts, chunkSums, offsets, cursor);

        if (tsp) {
            k_scat<1><<<(E_EVENTS + 255) / 256, 256, 0, stream>>>(node_ids, ts, cursor, permv);
            seg_attn<1><<<12500 * 5, 256, 0, stream>>>(
                permv, offsets, message, ts, nei1, nei2, msg_out, t_out, score);
        } else {
            k_scat<0><<<(E_EVENTS + 255) / 256, 256, 0, stream>>>(node_ids, ts, cursor, permv);
            seg_attn<0><<<12500 * 5, 256, 0, stream>>>(
                permv, offsets, message, ts, nei1, nei2, msg_out, t_out, score);
        }

        softmax_partial<<<128, 256, 0, stream>>>(score, partials);
        k_norm<<<(B_BATCH * K_NEI + 255) / 256, 256, 0, stream>>>(score, partials);
    }
}

// Round 13
// 426.562 us; speedup vs baseline: 4.3155x; 1.0004x over previous
//
#include <hip/hip_runtime.h>

#define N_NODES 200000
#define E_EVENTS 1000000
#define D_DIM 128
#define B_BATCH 50000
#define K_NEI 20
#define NCHUNK 196            // ceil(200000/1024)
#define PRIM_SLOTS 8          // compact primary slots/node (12.8 MB, L2-resident)
#define OVER_SLOTS 24         // overflow slots/node (total cap 32)

#define ATTN_SPLIT 10500      // attn units [0,10500) in fused kernel
#define ATTN_STEAL 2000       // attn units [10500,12500) run during scatter
#define SCAT_BLOCKS 3907      // ceil(1e6/256)

// ---------------- ws layout A: two-level slot path (52.02 MB) --------------
#define WA_CURSOR   0         // int[200000]
#define WA_PARTIALS 200064    // float2[128*20] -> ends 205184 (pad to 205440)
#define WA_PRIM     205440    // int2[200000*8]  -> ends 3405440
#define WA_OVER     3405440   // int2[200000*24] -> ends 13005440

// ---------------- ws layout B: CSR fallback (R9-proven) --------------------
#define WB_COUNTS   0
#define WB_OFFSETS  200000
#define WB_CURSOR   400000
#define WB_CHUNK    600000
#define WB_PARTIALS 600320
#define WB_PERM     605440

// ---------------------------------------------------------------------------
// attention logits for unit u (4 b's, one per wave) — verified R5..R12.
// ---------------------------------------------------------------------------
__device__ __forceinline__ void attn_unit(int u, int wid, int lane,
    const float* __restrict__ nei1, const float* __restrict__ nei2,
    float* __restrict__ logits)
{
    int b = u * 4 + wid;
    int c = lane & 31, h = lane >> 5;
    const float4* n2 = reinterpret_cast<const float4*>(nei2) + (size_t)b * (K_NEI * 32);
    float4 acc = make_float4(0.f, 0.f, 0.f, 0.f);
#pragma unroll
    for (int i = 0; i < K_NEI / 2; ++i) {
        float4 v = n2[(2 * i + h) * 32 + c];
        acc.x += v.x; acc.y += v.y; acc.z += v.z; acc.w += v.w;
    }
    float4 s4;
    s4.x = acc.x + __shfl_xor(acc.x, 32);
    s4.y = acc.y + __shfl_xor(acc.y, 32);
    s4.z = acc.z + __shfl_xor(acc.z, 32);
    s4.w = acc.w + __shfl_xor(acc.w, 32);

    const float4* n1 = reinterpret_cast<const float4*>(nei1) + (size_t)b * (K_NEI * 32);
    float p[K_NEI / 2];
#pragma unroll
    for (int i = 0; i < K_NEI / 2; ++i) {
        float4 v = n1[(2 * i + h) * 32 + c];
        float pp = v.x * s4.x + v.y * s4.y + v.z * s4.z + v.w * s4.w;
#pragma unroll
        for (int off = 16; off; off >>= 1) pp += __shfl_xor(pp, off);
        p[i] = pp;
    }
    int sel = c >> 1;
    float v = p[0];
#pragma unroll
    for (int i = 1; i < K_NEI / 2; ++i) v = (sel == i) ? p[i] : v;
    float vf = __shfl(v, ((lane & 1) << 5) + c);
    if (lane < K_NEI) logits[(size_t)b * K_NEI + lane] = vf;
}

// ---------------------------------------------------------------------------
// two-level slot segment reduce (R12-verified): one wave per node.
// ---------------------------------------------------------------------------
__device__ __forceinline__ void seg_node_slots(int n, int lane,
    const int2* __restrict__ prim, const int2* __restrict__ over,
    const int* __restrict__ cursor, const float* __restrict__ message,
    float* __restrict__ msg_out, float* __restrict__ t_out)
{
    int c = lane & 31, h = lane >> 5;
    int cnt = cursor[n];                                    // wave-uniform
    int2 pe = prim[(size_t)n * PRIM_SLOTS + (c & 7)];       // 64 B, indep of cnt
    int cl = min(cnt, PRIM_SLOTS + OVER_SLOTS);
    if (cl > PRIM_SLOTS && c >= PRIM_SLOTS && c < cl)       // rare (~7% of nodes)
        pe = over[(size_t)n * OVER_SLOTS + (c - PRIM_SLOTS)];

    int   e_l = pe.x;
    float t_l = (c < cl) ? __int_as_float(pe.y) : 0.f;

    const float4* msg4 = reinterpret_cast<const float4*>(message);
    float4 acc0 = make_float4(0.f, 0.f, 0.f, 0.f);
    float4 acc1 = make_float4(0.f, 0.f, 0.f, 0.f);
    float tmax = t_l;                                       // dup halves: max-safe

    int i = 0;
    for (; i + 8 <= cl; i += 8) {
        int eA = __shfl(e_l, i + 0 + h);
        int eB = __shfl(e_l, i + 2 + h);
        int eC = __shfl(e_l, i + 4 + h);
        int eD = __shfl(e_l, i + 6 + h);
        float4 vA = msg4[(size_t)eA * 32 + c];
        float4 vB = msg4[(size_t)eB * 32 + c];
        float4 vC = msg4[(size_t)eC * 32 + c];
        float4 vD = msg4[(size_t)eD * 32 + c];
        acc0.x += vA.x; acc0.y += vA.y; acc0.z += vA.z; acc0.w += vA.w;
        acc1.x += vB.x; acc1.y += vB.y; acc1.z += vB.z; acc1.w += vB.w;
        acc0.x += vC.x; acc0.y += vC.y; acc0.z += vC.z; acc0.w += vC.w;
        acc1.x += vD.x; acc1.y += vD.y; acc1.z += vD.z; acc1.w += vD.w;
    }
    for (; i + 2 <= cl; i += 2) {
        int e = __shfl(e_l, i + h);
        float4 v = msg4[(size_t)e * 32 + c];
        acc0.x += v.x; acc0.y += v.y; acc0.z += v.z; acc0.w += v.w;
    }
    if (i < cl) {
        int e = __shfl(e_l, i);
        if (h == 0) {
            float4 v = msg4[(size_t)e * 32 + c];
            acc0.x += v.x; acc0.y += v.y; acc0.z += v.z; acc0.w += v.w;
        }
    }

    float4 acc = make_float4(acc0.x + acc1.x, acc0.y + acc1.y,
                             acc0.z + acc1.z, acc0.w + acc1.w);
    acc.x += __shfl_xor(acc.x, 32);
    acc.y += __shfl_xor(acc.y, 32);
    acc.z += __shfl_xor(acc.z, 32);
    acc.w += __shfl_xor(acc.w, 32);
    float inv = 1.0f / (float)max(cnt, 1);
    if (h == 0) {
        reinterpret_cast<float4*>(msg_out)[(size_t)n * 32 + c] =
            make_float4(acc.x * inv, acc.y * inv, acc.z * inv, acc.w * inv);
    }
#pragma unroll
    for (int off = 32; off; off >>= 1) tmax = fmaxf(tmax, __shfl_xor(tmax, off));
    if (lane == 0) t_out[n] = tmax;
}

// ---------------------------------------------------------------------------
// scatter (blocks [0,3907)) || attn units [10500, 12500) (blocks [3907,5907)).
// Scatter is atomic-latency-bound; the attn stream uses the idle BW.
// ---------------------------------------------------------------------------
__global__ void k_scat_slots(const int* __restrict__ ids, const float* __restrict__ ts,
                             int* __restrict__ cursor,
                             int2* __restrict__ prim, int2* __restrict__ over,
                             const float* __restrict__ nei1, const float* __restrict__ nei2,
                             float* __restrict__ logits)
{
    int bid = blockIdx.x, t = threadIdx.x;
    if (bid < SCAT_BLOCKS) {
        int e = bid * 256 + t;
        if (e < E_EVENTS) {
            int id = ids[e];
            int pos = atomicAdd(cursor + id, 1);
            int2 rec = make_int2(e, __float_as_int(ts[e]));
            if (pos < PRIM_SLOTS)
                prim[(size_t)id * PRIM_SLOTS + pos] = rec;
            else if (pos < PRIM_SLOTS + OVER_SLOTS)
                over[(size_t)id * OVER_SLOTS + (pos - PRIM_SLOTS)] = rec;
        }
    } else {
        attn_unit(ATTN_SPLIT + (bid - SCAT_BLOCKS), t >> 6, t & 63, nei1, nei2, logits);
    }
}

// ---------------------------------------------------------------------------
// fused seg+attn — R5 5-block-group structure; attn only for g < ATTN_SPLIT.
// ---------------------------------------------------------------------------
__global__ void __launch_bounds__(256, 8)
seg_attn_slots(const int2* __restrict__ prim, const int2* __restrict__ over,
               const int* __restrict__ cursor, const float* __restrict__ message,
               const float* __restrict__ nei1, const float* __restrict__ nei2,
               float* __restrict__ msg_out, float* __restrict__ t_out,
               float* __restrict__ logits)
{
    int g = blockIdx.x / 5, r = blockIdx.x % 5;
    int t = threadIdx.x;
    int wid = t >> 6, lane = t & 63;

    if (r < 4) {
        int n = (g * 4 + r) * 4 + wid;            // covers 200000 exactly
        seg_node_slots(n, lane, prim, over, cursor, message, msg_out, t_out);
    } else if (g < ATTN_SPLIT) {
        attn_unit(g, wid, lane, nei1, nei2, logits);
    }
}

// ============================ CSR FALLBACK (R9) =============================
template<int TSP>
__device__ __forceinline__ void seg_node(int n, int lane,
    const void* __restrict__ permv, const int* __restrict__ offsets,
    const float* __restrict__ message, const float* __restrict__ ts,
    float* __restrict__ msg_out, float* __restrict__ t_out)
{
    int c = lane & 31, h = lane >> 5;
    int start = offsets[n];
    int end   = (n < N_NODES - 1) ? offsets[n + 1] : E_EVENTS;
    int len   = end - start;

    const float4* msg4 = reinterpret_cast<const float4*>(message);
    float4 acc0 = make_float4(0.f, 0.f, 0.f, 0.f);
    float4 acc1 = make_float4(0.f, 0.f, 0.f, 0.f);
    float tmax = 0.f;

    for (int base = start; base < end; base += 64) {
        int cl = min(end - base, 64);
        int e_l = 0; float t_l = 0.f;
        if (lane < cl) {
            if (TSP) {
                int2 pe = ((const int2*)permv)[base + lane];
                e_l = pe.x; t_l = __int_as_float(pe.y);
            } else {
                e_l = ((const int*)permv)[base + lane];
                t_l = ts[e_l];
            }
        }
        tmax = fmaxf(tmax, t_l);
        int i = 0;
        for (; i + 8 <= cl; i += 8) {
            int eA = __shfl(e_l, i + 0 + h);
            int eB = __shfl(e_l, i + 2 + h);
            int eC = __shfl(e_l, i + 4 + h);
            int eD = __shfl(e_l, i + 6 + h);
            float4 vA = msg4[(size_t)eA * 32 + c];
            float4 vB = msg4[(size_t)eB * 32 + c];
            float4 vC = msg4[(size_t)eC * 32 + c];
            float4 vD = msg4[(size_t)eD * 32 + c];
            acc0.x += vA.x; acc0.y += vA.y; acc0.z += vA.z; acc0.w += vA.w;
            acc1.x += vB.x; acc1.y += vB.y; acc1.z += vB.z; acc1.w += vB.w;
            acc0.x += vC.x; acc0.y += vC.y; acc0.z += vC.z; acc0.w += vC.w;
            acc1.x += vD.x; acc1.y += vD.y; acc1.z += vD.z; acc1.w += vD.w;
        }
        for (; i + 2 <= cl; i += 2) {
            int e = __shfl(e_l, i + h);
            float4 v = msg4[(size_t)e * 32 + c];
            acc0.x += v.x; acc0.y += v.y; acc0.z += v.z; acc0.w += v.w;
        }
        if (i < cl) {
            int e = __shfl(e_l, i);
            if (h == 0) {
                float4 v = msg4[(size_t)e * 32 + c];
                acc0.x += v.x; acc0.y += v.y; acc0.z += v.z; acc0.w += v.w;
            }
        }
    }
    float4 acc = make_float4(acc0.x + acc1.x, acc0.y + acc1.y,
                             acc0.z + acc1.z, acc0.w + acc1.w);
    acc.x += __shfl_xor(acc.x, 32);
    acc.y += __shfl_xor(acc.y, 32);
    acc.z += __shfl_xor(acc.z, 32);
    acc.w += __shfl_xor(acc.w, 32);
    float inv = 1.0f / (float)max(len, 1);
    if (h == 0) {
        reinterpret_cast<float4*>(msg_out)[(size_t)n * 32 + c] =
            make_float4(acc.x * inv, acc.y * inv, acc.z * inv, acc.w * inv);
    }
#pragma unroll
    for (int off = 32; off; off >>= 1) tmax = fmaxf(tmax, __shfl_xor(tmax, off));
    if (lane == 0) t_out[n] = tmax;
}

__global__ void k_hist(const int* __restrict__ ids, int* __restrict__ counts)
{
    int e = blockIdx.x * blockDim.x + threadIdx.x;
    if (e < E_EVENTS) atomicAdd(counts + ids[e], 1);
}

__global__ void __launch_bounds__(256)
k_scanb(const int* __restrict__ counts, int* __restrict__ chunkSums)
{
    __shared__ int sd[256];
    int t = threadIdx.x, base = blockIdx.x * 1024 + t * 4;
    int s = 0;
#pragma unroll
    for (int j = 0; j < 4; ++j) { int i = base + j; if (i < N_NODES) s += counts[i]; }
    sd[t] = s; __syncthreads();
    for (int off = 128; off; off >>= 1) {
        if (t < off) sd[t] += sd[t + off];
        __syncthreads();
    }
    if (t == 0) chunkSums[blockIdx.x] = sd[0];
}

__global__ void __launch_bounds__(256)
k_scanf(const int* __restrict__ counts, const int* __restrict__ chunkSums,
        int* __restrict__ offsets, int* __restrict__ cursor)
{
    __shared__ int sd[256];
    int bid = blockIdx.x, t = threadIdx.x;
    int v = (t < NCHUNK) ? chunkSums[t] : 0;
    sd[t] = v; __syncthreads();
    for (int off = 1; off < 256; off <<= 1) {
        int x = (t >= off) ? sd[t - off] : 0;
        __syncthreads();
        sd[t] += x;
        __syncthreads();
    }
    int chunkBase = (bid == 0) ? 0 : sd[bid - 1];
    __syncthreads();
    int base = bid * 1024 + t * 4;
    int c0 = (base + 0 < N_NODES) ? counts[base + 0] : 0;
    int c1 = (base + 1 < N_NODES) ? counts[base + 1] : 0;
    int c2 = (base + 2 < N_NODES) ? counts[base + 2] : 0;
    int c3 = (base + 3 < N_NODES) ? counts[base + 3] : 0;
    int tsum = c0 + c1 + c2 + c3;
    sd[t] = tsum; __syncthreads();
    for (int off = 1; off < 256; off <<= 1) {
        int x = (t >= off) ? sd[t - off] : 0;
        __syncthreads();
        sd[t] += x;
        __syncthreads();
    }
    int excl = sd[t] - tsum + chunkBase;
    if (base + 0 < N_NODES) { offsets[base + 0] = excl; cursor[base + 0] = excl; } excl += c0;
    if (base + 1 < N_NODES) { offsets[base + 1] = excl; cursor[base + 1] = excl; } excl += c1;
    if (base + 2 < N_NODES) { offsets[base + 2] = excl; cursor[base + 2] = excl; } excl += c2;
    if (base + 3 < N_NODES) { offsets[base + 3] = excl; cursor[base + 3] = excl; } excl += c3;
}

template<int TSP>
__global__ void k_scat(const int* __restrict__ ids, const float* __restrict__ ts,
                       int* __restrict__ cursor, void* __restrict__ permv)
{
    int e = blockIdx.x * blockDim.x + threadIdx.x;
    if (e < E_EVENTS) {
        int pos = atomicAdd(cursor + ids[e], 1);
        if (TSP) ((int2*)permv)[pos] = make_int2(e, __float_as_int(ts[e]));
        else     ((int*)permv)[pos]  = e;
    }
}

template<int TSP>
__global__ void __launch_bounds__(256, 8)
seg_attn(const void* __restrict__ permv, const int* __restrict__ offsets,
         const float* __restrict__ message, const float* __restrict__ ts,
         const float* __restrict__ nei1, const float* __restrict__ nei2,
         float* __restrict__ msg_out, float* __restrict__ t_out,
         float* __restrict__ logits)
{
    int g = blockIdx.x / 5, r = blockIdx.x % 5;
    int t = threadIdx.x;
    int wid = t >> 6, lane = t & 63;

    if (r < 4) {
        int n = (g * 4 + r) * 4 + wid;
        seg_node<TSP>(n, lane, permv, offsets, message, ts, msg_out, t_out);
    } else {
        attn_unit(g, wid, lane, nei1, nei2, logits);
    }
}
// ========================== end CSR fallback ================================

// ---------------------------------------------------------------------------
// softmax tail (shared): per-block partials + redundant-stats normalize.
// ---------------------------------------------------------------------------
__global__ void softmax_partial(const float* __restrict__ logits, float2* __restrict__ partials)
{
    int t = threadIdx.x;
    float m[K_NEI], s[K_NEI];
#pragma unroll
    for (int k = 0; k < K_NEI; ++k) { m[k] = -INFINITY; s[k] = 0.f; }

    for (int b = blockIdx.x * 256 + t; b < B_BATCH; b += 128 * 256) {
        const float4* row = reinterpret_cast<const float4*>(logits + (size_t)b * K_NEI);
        float v[K_NEI];
#pragma unroll
        for (int q = 0; q < 5; ++q) {
            float4 rr = row[q];
            v[q * 4 + 0] = rr.x; v[q * 4 + 1] = rr.y; v[q * 4 + 2] = rr.z; v[q * 4 + 3] = rr.w;
        }
#pragma unroll
        for (int k = 0; k < K_NEI; ++k) {
            float nm = fmaxf(m[k], v[k]);
            s[k] = s[k] * expf(m[k] - nm) + expf(v[k] - nm);
            m[k] = nm;
        }
    }
#pragma unroll
    for (int k = 0; k < K_NEI; ++k) {
#pragma unroll
        for (int off = 32; off; off >>= 1) {
            float om = __shfl_xor(m[k], off);
            float os = __shfl_xor(s[k], off);
            float nm = fmaxf(m[k], om);
            s[k] = s[k] * expf(m[k] - nm) + os * expf(om - nm);
            m[k] = nm;
        }
    }
    __shared__ float lm[4][K_NEI], lsum[4][K_NEI];
    int wid = t >> 6, lane = t & 63;
    if (lane == 0) {
#pragma unroll
        for (int k = 0; k < K_NEI; ++k) { lm[wid][k] = m[k]; lsum[wid][k] = s[k]; }
    }
    __syncthreads();
    if (t < K_NEI) {
        float mm = lm[0][t], ss = lsum[0][t];
#pragma unroll
        for (int w = 1; w < 4; ++w) {
            float om = lm[w][t], os = lsum[w][t];
            float nm = fmaxf(mm, om);
            ss = ss * expf(mm - nm) + os * expf(om - nm);
            mm = nm;
        }
        partials[blockIdx.x * K_NEI + t] = make_float2(mm, ss);
    }
}

__global__ void __launch_bounds__(256)
k_norm(float* __restrict__ score, const float2* __restrict__ partials)
{
    __shared__ float sm[256], ssum[256];
    __shared__ float stm[K_NEI], sinv[K_NEI];
    int t = threadIdx.x;
    float m = -INFINITY, s = 0.f;
    if (t < 240) {
        int k = t % K_NEI, g = t / K_NEI;
        int j0 = g * 11, j1 = min(j0 + 11, 128);
        for (int j = j0; j < j1; ++j) {
            float2 p = partials[j * K_NEI + k];
            float nm = fmaxf(m, p.x);
            s = s * expf(m - nm) + p.y * expf(p.x - nm);
            m = nm;
        }
    }
    sm[t] = m; ssum[t] = s; __syncthreads();
    if (t < K_NEI) {
        float mm = -INFINITY, ss = 0.f;
#pragma unroll
        for (int g = 0; g < 12; ++g) {
            float pm = sm[g * K_NEI + t], ps = ssum[g * K_NEI + t];
            float nm = fmaxf(mm, pm);
            ss = ss * expf(mm - nm) + ps * expf(pm - nm);
            mm = nm;
        }
        stm[t] = mm; sinv[t] = 1.0f / ss;
    }
    __syncthreads();
    int i = blockIdx.x * 256 + t;
    if (i < B_BATCH * K_NEI) {
        int k = i % K_NEI;
        score[i] = expf(score[i] - stm[k]) * sinv[k];
    }
}

extern "C" void kernel_launch(void* const* d_in, const int* in_sizes, int n_in,
                              void* d_out, int out_size, void* d_ws, size_t ws_size,
                              hipStream_t stream)
{
    const int*   node_ids = (const int*)  d_in[0];
    const float* message  = (const float*)d_in[1];
    const float* ts       = (const float*)d_in[2];
    const float* nei1     = (const float*)d_in[3];
    const float* nei2     = (const float*)d_in[4];

    float* out     = (float*)d_out;
    float* msg_out = out;                                   // [N,128]
    float* t_out   = out + (size_t)N_NODES * D_DIM;         // [N]
    float* score   = t_out + N_NODES;                       // [B,K]

    int* wsi = (int*)d_ws;

    size_t slots_need = ((size_t)WA_OVER + 2u * (size_t)N_NODES * OVER_SLOTS) * sizeof(int);

    if (ws_size >= slots_need) {
        int*    cursor   = wsi + WA_CURSOR;
        float2* partials = (float2*)(wsi + WA_PARTIALS);
        int2*   prim     = (int2*)(wsi + WA_PRIM);
        int2*   over     = (int2*)(wsi + WA_OVER);

        hipMemsetAsync(cursor, 0, (size_t)N_NODES * sizeof(int), stream);

        k_scat_slots<<<SCAT_BLOCKS + ATTN_STEAL, 256, 0, stream>>>(
            node_ids, ts, cursor, prim, over, nei1, nei2, score);
        seg_attn_slots<<<12500 * 5, 256, 0, stream>>>(
            prim, over, cursor, message, nei1, nei2, msg_out, t_out, score);
        softmax_partial<<<128, 256, 0, stream>>>(score, partials);
        k_norm<<<(B_BATCH * K_NEI + 255) / 256, 256, 0, stream>>>(score, partials);
    } else {
        // -------- CSR fallback (R9-proven) ----------------------------------
        int*    counts    = wsi + WB_COUNTS;
        int*    offsets   = wsi + WB_OFFSETS;
        int*    cursor    = wsi + WB_CURSOR;
        int*    chunkSums = wsi + WB_CHUNK;
        float2* partials  = (float2*)(wsi + WB_PARTIALS);
        void*   permv     = (void*)(wsi + WB_PERM);

        bool tsp = ws_size >= ((size_t)WB_PERM + 2u * E_EVENTS) * sizeof(int);

        hipMemsetAsync(counts, 0, (size_t)N_NODES * sizeof(int), stream);

        k_hist<<<(E_EVENTS + 255) / 256, 256, 0, stream>>>(node_ids, counts);
        k_scanb<<<NCHUNK, 256, 0, stream>>>(counts, chunkSums);
        k_scanf<<<NCHUNK, 256, 0, stream>>>(counts, chunkSums, offsets, cursor);

        if (tsp) {
            k_scat<1><<<(E_EVENTS + 255) / 256, 256, 0, stream>>>(node_ids, ts, cursor, permv);
            seg_attn<1><<<12500 * 5, 256, 0, stream>>>(
                permv, offsets, message, ts, nei1, nei2, msg_out, t_out, score);
        } else {
            k_scat<0><<<(E_EVENTS + 255) / 256, 256, 0, stream>>>(node_ids, ts, cursor, permv);
            seg_attn<0><<<12500 * 5, 256, 0, stream>>>(
                permv, offsets, message, ts, nei1, nei2, msg_out, t_out, score);
        }

        softmax_partial<<<128, 256, 0, stream>>>(score, partials);
        k_norm<<<(B_BATCH * K_NEI + 255) / 256, 256, 0, stream>>>(score, partials);
    }
}